// Round 6
// baseline (460.423 us; speedup 1.0000x reference)
//
#include <hip/hip_runtime.h>
#include <hip/hip_bf16.h>

#define BB 32
#define TT 64
#define NN 512
#define HH 64

using u16 = unsigned short;
using u32 = unsigned int;
typedef __attribute__((ext_vector_type(8))) short bf16x8;
typedef __attribute__((ext_vector_type(4))) float f32x4;

__device__ __forceinline__ float bf2f(u16 u) {
  union { u32 i; float f; } v; v.i = ((u32)u) << 16; return v.f;
}
__device__ __forceinline__ u16 f2bf(float f) {
  __hip_bfloat16 h = __float2bfloat16(f);
  u16 u; __builtin_memcpy(&u, &h, 2); return u;
}

// async global->LDS, 16B per lane; lds base must be wave-uniform,
// lane i lands at ldsbase + i*16; GLOBAL address is per-lane (must include
// the lane term explicitly).
__device__ __forceinline__ void gld_lds16(const void* g, void* l) {
  __builtin_amdgcn_global_load_lds(
      (const __attribute__((address_space(1))) u32*)g,
      (__attribute__((address_space(3))) u32*)l, 16, 0, 0);
}

// ---------------------------------------------------------------------------
// conversion kernels (run once per call)
// ---------------------------------------------------------------------------
__global__ __launch_bounds__(256) void kcvt_adj(const float* __restrict__ a,
                                                u16* __restrict__ o) {
  const int i = blockIdx.x * 256 + threadIdx.x;  // 262144 total
  o[i] = f2bf(a[i]);
}
__global__ __launch_bounds__(256) void kcvt_w2t(const float* __restrict__ w2,
                                                u16* __restrict__ o) {
  const int i = blockIdx.x * 256 + threadIdx.x;  // 2048 total, o[h*32+c]
  const int h = i >> 5, c = i & 31;
  o[i] = f2bf(w2[c * 64 + h]);
}
// tcn_w [n][ho][hi][kk] (fp32) -> Wb [n][kk][ho][hi] (bf16)
__global__ __launch_bounds__(256) void kcvt_w(const float* __restrict__ tw,
                                              u16* __restrict__ o) {
  const int i = blockIdx.x * 256 + threadIdx.x;  // 6291456 total
  const int hi = i & 63;
  const int ho = (i >> 6) & 63;
  const int r = i >> 12;  // n*3 + kk
  const int n = r / 3, kk = r - n * 3;
  o[i] = f2bf(tw[(n * 64 + ho) * 192 + hi * 3 + kk]);
}

// ---------------------------------------------------------------------------
// K0: S[bt][u] = sum_v X[bt][v] * adj[u][v]   (fp32 VALU, 1.07 GF — cheap)
// ---------------------------------------------------------------------------
__global__ __launch_bounds__(256) void k0_s(const float* __restrict__ xg,
                                            const float* __restrict__ adjg,
                                            float* __restrict__ Sg) {
  __shared__ __align__(16) float XsT[64][68];
  __shared__ __align__(16) float AdjT[64][68];
  const int tid = threadIdx.x;
  const int bt0 = blockIdx.x * 64, u0 = blockIdx.y * 64;
  const int ty = tid >> 4, tx = tid & 15;
  const int r = tid >> 2, cb = (tid & 3) << 4;
  float acc[4][4] = {};
  for (int v0 = 0; v0 < NN; v0 += 64) {
    {
      const float4* p = (const float4*)(xg + (((size_t)(bt0 + r)) << 9) + v0 + cb);
#pragma unroll
      for (int q = 0; q < 4; ++q) {
        float4 v = p[q];
        XsT[cb + q * 4 + 0][r] = v.x; XsT[cb + q * 4 + 1][r] = v.y;
        XsT[cb + q * 4 + 2][r] = v.z; XsT[cb + q * 4 + 3][r] = v.w;
      }
      const float4* pa = (const float4*)(adjg + (((size_t)(u0 + r)) << 9) + v0 + cb);
#pragma unroll
      for (int q = 0; q < 4; ++q) {
        float4 v = pa[q];
        AdjT[cb + q * 4 + 0][r] = v.x; AdjT[cb + q * 4 + 1][r] = v.y;
        AdjT[cb + q * 4 + 2][r] = v.z; AdjT[cb + q * 4 + 3][r] = v.w;
      }
    }
    __syncthreads();
#pragma unroll 8
    for (int v = 0; v < 64; ++v) {
      const float4 av = *(const float4*)&XsT[v][ty * 4];
      const float4 bv = *(const float4*)&AdjT[v][tx * 4];
      const float a[4] = {av.x, av.y, av.z, av.w};
      const float b[4] = {bv.x, bv.y, bv.z, bv.w};
#pragma unroll
      for (int i = 0; i < 4; ++i)
#pragma unroll
        for (int j = 0; j < 4; ++j) acc[i][j] += a[i] * b[j];
    }
    __syncthreads();
  }
#pragma unroll
  for (int i = 0; i < 4; ++i) {
    float4 o = {acc[i][0], acc[i][1], acc[i][2], acc[i][3]};
    *(float4*)&Sg[((size_t)(bt0 + ty * 4 + i)) * NN + u0 + tx * 4] = o;
  }
}

// ---------------------------------------------------------------------------
// K1 (MFMA): G[(bp,t,h)][v] = sum_c relu(w1[c]*S[bt,v]+b1[c]) * w2[c][h]
// grid (T, CB); per wave: 64h x 128v, K=32 in one MFMA step, B built in-reg.
// ---------------------------------------------------------------------------
__global__ __launch_bounds__(256) void k1_g(const float* __restrict__ Sg,
                                            const float* __restrict__ w1g,
                                            const float* __restrict__ b1g,
                                            const u16* __restrict__ w2t,
                                            u16* __restrict__ Gg, int b0) {
  const int tid = threadIdx.x;
  const int t = blockIdx.x, bp = blockIdx.y;
  const int w = tid >> 6, l = tid & 63;
  const int quad = l >> 4, lr = l & 15;
  const size_t sRow = ((size_t)((b0 + bp) * TT + t)) * NN;
  const size_t gBase = ((size_t)(bp * TT + t)) * HH * NN;
  float w1v[8], b1v[8];
#pragma unroll
  for (int j = 0; j < 8; ++j) { w1v[j] = w1g[quad * 8 + j]; b1v[j] = b1g[quad * 8 + j]; }
  bf16x8 af[4];
#pragma unroll
  for (int i = 0; i < 4; ++i)
    af[i] = *(const bf16x8*)(w2t + (i * 16 + lr) * 32 + quad * 8);
  const f32x4 zz = {0.f, 0.f, 0.f, 0.f};
  for (int vp = 0; vp < 2; ++vp) {
    const int v0 = w * 128 + vp * 64;
    f32x4 acc[4][4];
#pragma unroll
    for (int i = 0; i < 4; ++i)
#pragma unroll
      for (int j = 0; j < 4; ++j) acc[i][j] = zz;
    bf16x8 bfr[4];
#pragma unroll
    for (int j = 0; j < 4; ++j) {
      const int v = v0 + j * 16 + lr;
      const float sv = Sg[sRow + v];
      bf16x8 x;
#pragma unroll
      for (int jj = 0; jj < 8; ++jj)
        x[jj] = (short)f2bf(fmaxf(fmaf(w1v[jj], sv, b1v[jj]), 0.f));
      bfr[j] = x;
    }
#pragma unroll
    for (int i = 0; i < 4; ++i)
#pragma unroll
      for (int j = 0; j < 4; ++j)
        acc[i][j] = __builtin_amdgcn_mfma_f32_16x16x32_bf16(af[i], bfr[j], acc[i][j], 0, 0, 0);
#pragma unroll
    for (int i = 0; i < 4; ++i)
#pragma unroll
      for (int j = 0; j < 4; ++j) {
        const int v = v0 + j * 16 + lr;
#pragma unroll
        for (int r = 0; r < 4; ++r) {
          const int h = i * 16 + quad * 4 + r;
          Gg[gBase + (size_t)h * NN + v] = f2bf(acc[i][j][r]);
        }
      }
  }
}

// ---------------------------------------------------------------------------
// K2 (MFMA GEMM, m97-style): C[u][n] = relu(sum_v A[u][v]*B[n][v] + b2[n&63])
// A = adj bf16 [512][512], B = G [Nc][512], C = H2 bf16 [512][Nc].
// 128x128 tile, BK=64, global_load_lds w16, XOR-swizzled LDS, 2x2 waves.
// C written with per-row swizzle: 16B unit c of (t)-row stored at c^(t&7)
// so K3's LDS staging is bank-conflict-free.
// ---------------------------------------------------------------------------
__global__ __launch_bounds__(256) void k2_gemm(const u16* __restrict__ A,
                                               const u16* __restrict__ Bm,
                                               const float* __restrict__ b2g,
                                               u16* __restrict__ C, int Nc) {
  __shared__ __align__(16) char smem[32768];  // As 16KB | Bs 16KB
  const int tid = threadIdx.x;
  const int w = tid >> 6, l = tid & 63;
  const int quad = l >> 4, lr = l & 15;
  const int tn = blockIdx.x, tm = blockIdx.y;
  const int m0 = tm * 128, n0 = tn * 128;
  const int wm = w >> 1, wn = w & 1;
  // staging: inst (w,c) covers rows c*32+w*8 .. +8, lane i -> (row base+i>>3, unit i&7)
  const int rB = w * 8 + (l >> 3);
  const int uu = l & 7;
  const u16* agp[4]; const u16* bgp[4];
#pragma unroll
  for (int c = 0; c < 4; ++c) {
    const int r = rB + c * 32;
    agp[c] = A + (size_t)(m0 + r) * 512 + ((uu ^ (r & 7)) * 8);
    bgp[c] = Bm + (size_t)(n0 + r) * 512 + ((uu ^ (r & 7)) * 8);
  }
  char* As = smem;
  char* Bs = smem + 16384;
  int arow[4], brow[4];
#pragma unroll
  for (int i = 0; i < 4; ++i) {
    arow[i] = (wm * 64 + i * 16 + lr) * 128;
    brow[i] = (wn * 64 + i * 16 + lr) * 128;
  }
  const f32x4 zz = {0.f, 0.f, 0.f, 0.f};
  f32x4 acc[4][4];
#pragma unroll
  for (int i = 0; i < 4; ++i)
#pragma unroll
    for (int j = 0; j < 4; ++j) acc[i][j] = zz;
  const int lx7 = lr & 7;
  for (int kt = 0; kt < 8; ++kt) {
#pragma unroll
    for (int c = 0; c < 4; ++c) {
      gld_lds16(agp[c] + kt * 64, As + (c * 32 + w * 8) * 128);
      gld_lds16(bgp[c] + kt * 64, Bs + (c * 32 + w * 8) * 128);
    }
    __syncthreads();
#pragma unroll
    for (int ks = 0; ks < 2; ++ks) {
      const int coff = (((ks * 4 + quad) ^ lx7)) * 16;
      bf16x8 afr[4], bfr[4];
#pragma unroll
      for (int i = 0; i < 4; ++i) afr[i] = *(const bf16x8*)(As + arow[i] + coff);
#pragma unroll
      for (int j = 0; j < 4; ++j) bfr[j] = *(const bf16x8*)(Bs + brow[j] + coff);
#pragma unroll
      for (int i = 0; i < 4; ++i)
#pragma unroll
        for (int j = 0; j < 4; ++j)
          acc[i][j] = __builtin_amdgcn_mfma_f32_16x16x32_bf16(afr[i], bfr[j], acc[i][j], 0, 0, 0);
    }
    __syncthreads();
  }
  // epilogue: bias+relu, write with per-(t)-row XOR swizzle on 16B units
  const int nb = n0 + wn * 64;          // 64-aligned base col
  const int tcol = (nb >> 6) & 63;
  const int bpcol = nb >> 12;
  const int tx7 = tcol & 7;
  float bias[4];
#pragma unroll
  for (int j = 0; j < 4; ++j) bias[j] = b2g[j * 16 + lr];  // true h = j*16+lr
#pragma unroll
  for (int j = 0; j < 4; ++j) {
    const int h = j * 16 + lr;
    const int hsw = (((h >> 3) ^ tx7) << 3) | (h & 7);
    const size_t colb = (size_t)bpcol * 4096 + tcol * 64 + hsw;
#pragma unroll
    for (int i = 0; i < 4; ++i) {
      const int u0r = m0 + wm * 64 + i * 16 + quad * 4;
#pragma unroll
      for (int r = 0; r < 4; ++r) {
        const float vv = fmaxf(acc[i][j][r] + bias[j], 0.f);
        C[(size_t)(u0r + r) * Nc + colb] = f2bf(vv);
      }
    }
  }
}

// ---------------------------------------------------------------------------
// K3 (MFMA): grid (NN) x 4 waves. Wave owns (n, bp=w+4*it): W frags
// register-resident (24 frags, reused across bp), H2 slab staged to
// wave-private LDS (8KB, swizzled rows -> conflict-free ds_read_b128),
// conv = 3 shifted K=64 GEMMs, fused bias+relu+FC reduce.
// ---------------------------------------------------------------------------
__global__ __launch_bounds__(256, 2) void k3_tcn(const u16* __restrict__ H2,
                                                 const u16* __restrict__ Wb,
                                                 const float* __restrict__ tbg,
                                                 const float* __restrict__ fwg,
                                                 const float* __restrict__ fbg,
                                                 float* __restrict__ outg,
                                                 int b0, int Nc, int CBcur) {
  __shared__ __align__(16) char hlds[4][8192];
  const int tid = threadIdx.x;
  const int n = blockIdx.x;
  const int w = tid >> 6, l = tid & 63;
  const int quad = l >> 4, lr = l & 15;
  const u16* Wp = Wb + (size_t)n * 12288;
  // register-resident W frags: af[kk][ks][i]
  bf16x8 af[3][2][4];
#pragma unroll
  for (int kk = 0; kk < 3; ++kk)
#pragma unroll
    for (int ks = 0; ks < 2; ++ks)
#pragma unroll
      for (int i = 0; i < 4; ++i)
        af[kk][ks][i] =
            *(const bf16x8*)(Wp + kk * 4096 + (i * 16 + lr) * 64 + ks * 32 + quad * 8);
  float tbv[4][4];
#pragma unroll
  for (int i = 0; i < 4; ++i)
#pragma unroll
    for (int r = 0; r < 4; ++r) tbv[i][r] = tbg[n * 64 + i * 16 + quad * 4 + r];
  const float fcb = fbg[0];
  bf16x8 bz;
#pragma unroll
  for (int jj = 0; jj < 8; ++jj) bz[jj] = 0;
  char* myl = hlds[w];
  const f32x4 zz = {0.f, 0.f, 0.f, 0.f};
  for (int bp = w; bp < CBcur; bp += 4) {
    const u16* Hs = H2 + (size_t)n * Nc + bp * 4096;
    // all prior ds_reads consumed; safe to overwrite wave-private region
    asm volatile("s_waitcnt lgkmcnt(0)" ::: "memory");
#pragma unroll
    for (int c = 0; c < 8; ++c)
      gld_lds16(Hs + c * 512 + (size_t)l * 8, myl + c * 1024);  // per-lane gaddr!
    asm volatile("s_waitcnt vmcnt(0)" ::: "memory");
    f32x4 acc[4][4];
#pragma unroll
    for (int i = 0; i < 4; ++i)
#pragma unroll
      for (int j = 0; j < 4; ++j) acc[i][j] = zz;
#pragma unroll
    for (int ks = 0; ks < 2; ++ks)
#pragma unroll
      for (int kk = 0; kk < 3; ++kk) {
        bf16x8 bfr[4];
#pragma unroll
        for (int j = 0; j < 4; ++j) {
          const int tau = j * 16 + lr + kk - 1;
          const int tc = min(max(tau, 0), 63);
          const int off = tc * 128 + (((ks * 4 + quad) ^ (tc & 7)) << 4);
          const bf16x8 v = *(const bf16x8*)(myl + off);
          bfr[j] = (tau == tc) ? v : bz;
        }
#pragma unroll
        for (int i = 0; i < 4; ++i)
#pragma unroll
          for (int j = 0; j < 4; ++j)
            acc[i][j] = __builtin_amdgcn_mfma_f32_16x16x32_bf16(af[kk][ks][i], bfr[j],
                                                                acc[i][j], 0, 0, 0);
      }
    // epilogue: bias + relu + FC dot, all in-wave
    float part = 0.f;
#pragma unroll
    for (int i = 0; i < 4; ++i)
#pragma unroll
      for (int r = 0; r < 4; ++r) {
        const int ho = i * 16 + quad * 4 + r;
        const float* fwp = fwg + ho * 64 + lr;
#pragma unroll
        for (int j = 0; j < 4; ++j)
          part += fmaxf(acc[i][j][r] + tbv[i][r], 0.f) * fwp[j * 16];
      }
#pragma unroll
    for (int off = 32; off > 0; off >>= 1) part += __shfl_xor(part, off, 64);
    if (l == 0) outg[(size_t)(b0 + bp) * NN + n] = part + fcb;
  }
}

// ---------------------------------------------------------------------------
extern "C" void kernel_launch(void* const* d_in, const int* in_sizes, int n_in,
                              void* d_out, int out_size, void* d_ws, size_t ws_size,
                              hipStream_t stream) {
  const float* xg   = (const float*)d_in[0];
  const float* adjg = (const float*)d_in[1];
  const float* w1g  = (const float*)d_in[2];
  const float* b1g  = (const float*)d_in[3];
  const float* w2g  = (const float*)d_in[4];
  const float* b2g  = (const float*)d_in[5];
  const float* twg  = (const float*)d_in[6];
  const float* tbg  = (const float*)d_in[7];
  const float* fwg  = (const float*)d_in[8];
  const float* fbg  = (const float*)d_in[9];
  float* outg = (float*)d_out;

  char* ws = (char*)d_ws;
  float* Sg = (float*)ws;                      // 4,194,304 B
  u16* adjb = (u16*)(ws + 4194304);            //   524,288 B
  u16* w2t  = (u16*)(ws + 4718592);            //     8,192 B (4KB used)
  u16* Wb   = (u16*)(ws + 4726784);            // 12,582,912 B
  const size_t fixedB = 17309696;
  int CB = 32;
  while (CB > 1 && fixedB + (size_t)CB * 8388608ull > ws_size) CB >>= 1;
  u16* Gg  = (u16*)(ws + fixedB);
  u16* H2g = Gg + (size_t)CB * 2097152;  // CB*4096 rows x 512
  const int Nc = CB * 4096;

  kcvt_adj<<<1024, 256, 0, stream>>>(adjg, adjb);
  kcvt_w2t<<<8, 256, 0, stream>>>(w2g, w2t);
  kcvt_w<<<24576, 256, 0, stream>>>(twg, Wb);
  k0_s<<<dim3(BB * TT / 64, NN / 64), 256, 0, stream>>>(xg, adjg, Sg);
  for (int b0 = 0; b0 < BB; b0 += CB) {
    k1_g<<<dim3(TT, CB), 256, 0, stream>>>(Sg, w1g, b1g, w2t, Gg, b0);
    k2_gemm<<<dim3(Nc / 128, 4), 256, 0, stream>>>(adjb, Gg, b2g, H2g, Nc);
    k3_tcn<<<dim3(NN), 256, 0, stream>>>(H2g, Wb, tbg, fwg, fbg, outg, b0, Nc, CB);
  }
}

// Round 7
// 354.447 us; speedup vs baseline: 1.2990x; 1.2990x over previous
//
#include <hip/hip_runtime.h>
#include <hip/hip_bf16.h>

#define BB 32
#define TT 64
#define NN 512
#define HH 64

using u16 = unsigned short;
using u32 = unsigned int;
typedef __attribute__((ext_vector_type(8))) short bf16x8;
typedef __attribute__((ext_vector_type(4))) float f32x4;

__device__ __forceinline__ float bf2f(u16 u) {
  union { u32 i; float f; } v; v.i = ((u32)u) << 16; return v.f;
}
__device__ __forceinline__ u16 f2bf(float f) {
  __hip_bfloat16 h = __float2bfloat16(f);
  u16 u; __builtin_memcpy(&u, &h, 2); return u;
}

// async global->LDS, 16B per lane; lds base must be wave-uniform,
// lane i lands at ldsbase + i*16; GLOBAL address is per-lane (must include
// the lane term explicitly).
__device__ __forceinline__ void gld_lds16(const void* g, void* l) {
  __builtin_amdgcn_global_load_lds(
      (const __attribute__((address_space(1))) u32*)g,
      (__attribute__((address_space(3))) u32*)l, 16, 0, 0);
}

// ---------------------------------------------------------------------------
// conversion kernels (run once per call)
// ---------------------------------------------------------------------------
__global__ __launch_bounds__(256) void kcvt_adj(const float* __restrict__ a,
                                                u16* __restrict__ o) {
  const int i = blockIdx.x * 256 + threadIdx.x;  // 262144 total
  o[i] = f2bf(a[i]);
}
__global__ __launch_bounds__(256) void kcvt_w2t(const float* __restrict__ w2,
                                                u16* __restrict__ o) {
  const int i = blockIdx.x * 256 + threadIdx.x;  // 2048 total, o[h*32+c]
  const int h = i >> 5, c = i & 31;
  o[i] = f2bf(w2[c * 64 + h]);
}
// tcn_w [n][ho][hi][kk] (fp32) -> Wb [n][kk][ho][hi'] (bf16), where the
// 16B unit of hi is XOR-swizzled by (ho&7) so K3's linear LDS staging gives
// conflict-free ds_read_b128 of A-frags.
__global__ __launch_bounds__(256) void kcvt_w(const float* __restrict__ tw,
                                              u16* __restrict__ o) {
  const int i = blockIdx.x * 256 + threadIdx.x;  // 6291456 total
  const int his = i & 63;                        // stored hi position
  const int ho = (i >> 6) & 63;
  const int r = i >> 12;  // n*3 + kk
  const int n = r / 3, kk = r - n * 3;
  const int hi = (((his >> 3) ^ (ho & 7)) << 3) | (his & 7);  // logical hi
  o[i] = f2bf(tw[(n * 64 + ho) * 192 + hi * 3 + kk]);
}

// ---------------------------------------------------------------------------
// K0: S[bt][u] = sum_v X[bt][v] * adj[u][v]   (fp32 VALU, 1.07 GF — cheap)
// ---------------------------------------------------------------------------
__global__ __launch_bounds__(256) void k0_s(const float* __restrict__ xg,
                                            const float* __restrict__ adjg,
                                            float* __restrict__ Sg) {
  __shared__ __align__(16) float XsT[64][68];
  __shared__ __align__(16) float AdjT[64][68];
  const int tid = threadIdx.x;
  const int bt0 = blockIdx.x * 64, u0 = blockIdx.y * 64;
  const int ty = tid >> 4, tx = tid & 15;
  const int r = tid >> 2, cb = (tid & 3) << 4;
  float acc[4][4] = {};
  for (int v0 = 0; v0 < NN; v0 += 64) {
    {
      const float4* p = (const float4*)(xg + (((size_t)(bt0 + r)) << 9) + v0 + cb);
#pragma unroll
      for (int q = 0; q < 4; ++q) {
        float4 v = p[q];
        XsT[cb + q * 4 + 0][r] = v.x; XsT[cb + q * 4 + 1][r] = v.y;
        XsT[cb + q * 4 + 2][r] = v.z; XsT[cb + q * 4 + 3][r] = v.w;
      }
      const float4* pa = (const float4*)(adjg + (((size_t)(u0 + r)) << 9) + v0 + cb);
#pragma unroll
      for (int q = 0; q < 4; ++q) {
        float4 v = pa[q];
        AdjT[cb + q * 4 + 0][r] = v.x; AdjT[cb + q * 4 + 1][r] = v.y;
        AdjT[cb + q * 4 + 2][r] = v.z; AdjT[cb + q * 4 + 3][r] = v.w;
      }
    }
    __syncthreads();
#pragma unroll 8
    for (int v = 0; v < 64; ++v) {
      const float4 av = *(const float4*)&XsT[v][ty * 4];
      const float4 bv = *(const float4*)&AdjT[v][tx * 4];
      const float a[4] = {av.x, av.y, av.z, av.w};
      const float b[4] = {bv.x, bv.y, bv.z, bv.w};
#pragma unroll
      for (int i = 0; i < 4; ++i)
#pragma unroll
        for (int j = 0; j < 4; ++j) acc[i][j] += a[i] * b[j];
    }
    __syncthreads();
  }
#pragma unroll
  for (int i = 0; i < 4; ++i) {
    float4 o = {acc[i][0], acc[i][1], acc[i][2], acc[i][3]};
    *(float4*)&Sg[((size_t)(bt0 + ty * 4 + i)) * NN + u0 + tx * 4] = o;
  }
}

// ---------------------------------------------------------------------------
// K1 (MFMA): G[(bp,t,h)][v] = sum_c relu(w1[c]*S[bt,v]+b1[c]) * w2[c][h]
// grid (T, CB); per wave: 64h x 128v, K=32 in one MFMA step, B built in-reg.
// ---------------------------------------------------------------------------
__global__ __launch_bounds__(256) void k1_g(const float* __restrict__ Sg,
                                            const float* __restrict__ w1g,
                                            const float* __restrict__ b1g,
                                            const u16* __restrict__ w2t,
                                            u16* __restrict__ Gg, int b0) {
  const int tid = threadIdx.x;
  const int t = blockIdx.x, bp = blockIdx.y;
  const int w = tid >> 6, l = tid & 63;
  const int quad = l >> 4, lr = l & 15;
  const size_t sRow = ((size_t)((b0 + bp) * TT + t)) * NN;
  const size_t gBase = ((size_t)(bp * TT + t)) * HH * NN;
  float w1v[8], b1v[8];
#pragma unroll
  for (int j = 0; j < 8; ++j) { w1v[j] = w1g[quad * 8 + j]; b1v[j] = b1g[quad * 8 + j]; }
  bf16x8 af[4];
#pragma unroll
  for (int i = 0; i < 4; ++i)
    af[i] = *(const bf16x8*)(w2t + (i * 16 + lr) * 32 + quad * 8);
  const f32x4 zz = {0.f, 0.f, 0.f, 0.f};
  for (int vp = 0; vp < 2; ++vp) {
    const int v0 = w * 128 + vp * 64;
    f32x4 acc[4][4];
#pragma unroll
    for (int i = 0; i < 4; ++i)
#pragma unroll
      for (int j = 0; j < 4; ++j) acc[i][j] = zz;
    bf16x8 bfr[4];
#pragma unroll
    for (int j = 0; j < 4; ++j) {
      const int v = v0 + j * 16 + lr;
      const float sv = Sg[sRow + v];
      bf16x8 x;
#pragma unroll
      for (int jj = 0; jj < 8; ++jj)
        x[jj] = (short)f2bf(fmaxf(fmaf(w1v[jj], sv, b1v[jj]), 0.f));
      bfr[j] = x;
    }
#pragma unroll
    for (int i = 0; i < 4; ++i)
#pragma unroll
      for (int j = 0; j < 4; ++j)
        acc[i][j] = __builtin_amdgcn_mfma_f32_16x16x32_bf16(af[i], bfr[j], acc[i][j], 0, 0, 0);
#pragma unroll
    for (int i = 0; i < 4; ++i)
#pragma unroll
      for (int j = 0; j < 4; ++j) {
        const int v = v0 + j * 16 + lr;
#pragma unroll
        for (int r = 0; r < 4; ++r) {
          const int h = i * 16 + quad * 4 + r;
          Gg[gBase + (size_t)h * NN + v] = f2bf(acc[i][j][r]);
        }
      }
  }
}

// ---------------------------------------------------------------------------
// K2 (MFMA GEMM, m97-style): C[u][n] = relu(sum_v A[u][v]*B[n][v] + b2[n&63])
// A = adj bf16 [512][512], B = G [Nc][512], C = H2 bf16 [512][Nc].
// 128x128 tile, BK=64, global_load_lds w16, XOR-swizzled LDS, 2x2 waves.
// C written with per-row swizzle: 16B unit c of (t)-row stored at c^(t&7)
// so K3's LDS staging is bank-conflict-free.
// ---------------------------------------------------------------------------
__global__ __launch_bounds__(256) void k2_gemm(const u16* __restrict__ A,
                                               const u16* __restrict__ Bm,
                                               const float* __restrict__ b2g,
                                               u16* __restrict__ C, int Nc) {
  __shared__ __align__(16) char smem[32768];  // As 16KB | Bs 16KB
  const int tid = threadIdx.x;
  const int w = tid >> 6, l = tid & 63;
  const int quad = l >> 4, lr = l & 15;
  const int tn = blockIdx.x, tm = blockIdx.y;
  const int m0 = tm * 128, n0 = tn * 128;
  const int wm = w >> 1, wn = w & 1;
  // staging: inst (w,c) covers rows c*32+w*8 .. +8, lane i -> (row base+i>>3, unit i&7)
  const int rB = w * 8 + (l >> 3);
  const int uu = l & 7;
  const u16* agp[4]; const u16* bgp[4];
#pragma unroll
  for (int c = 0; c < 4; ++c) {
    const int r = rB + c * 32;
    agp[c] = A + (size_t)(m0 + r) * 512 + ((uu ^ (r & 7)) * 8);
    bgp[c] = Bm + (size_t)(n0 + r) * 512 + ((uu ^ (r & 7)) * 8);
  }
  char* As = smem;
  char* Bs = smem + 16384;
  int arow[4], brow[4];
#pragma unroll
  for (int i = 0; i < 4; ++i) {
    arow[i] = (wm * 64 + i * 16 + lr) * 128;
    brow[i] = (wn * 64 + i * 16 + lr) * 128;
  }
  const f32x4 zz = {0.f, 0.f, 0.f, 0.f};
  f32x4 acc[4][4];
#pragma unroll
  for (int i = 0; i < 4; ++i)
#pragma unroll
    for (int j = 0; j < 4; ++j) acc[i][j] = zz;
  const int lx7 = lr & 7;
  for (int kt = 0; kt < 8; ++kt) {
#pragma unroll
    for (int c = 0; c < 4; ++c) {
      gld_lds16(agp[c] + kt * 64, As + (c * 32 + w * 8) * 128);
      gld_lds16(bgp[c] + kt * 64, Bs + (c * 32 + w * 8) * 128);
    }
    __syncthreads();
#pragma unroll
    for (int ks = 0; ks < 2; ++ks) {
      const int coff = (((ks * 4 + quad) ^ lx7)) * 16;
      bf16x8 afr[4], bfr[4];
#pragma unroll
      for (int i = 0; i < 4; ++i) afr[i] = *(const bf16x8*)(As + arow[i] + coff);
#pragma unroll
      for (int j = 0; j < 4; ++j) bfr[j] = *(const bf16x8*)(Bs + brow[j] + coff);
#pragma unroll
      for (int i = 0; i < 4; ++i)
#pragma unroll
        for (int j = 0; j < 4; ++j)
          acc[i][j] = __builtin_amdgcn_mfma_f32_16x16x32_bf16(afr[i], bfr[j], acc[i][j], 0, 0, 0);
    }
    __syncthreads();
  }
  // epilogue: bias+relu, write with per-(t)-row XOR swizzle on 16B units
  const int nb = n0 + wn * 64;          // 64-aligned base col
  const int tcol = (nb >> 6) & 63;
  const int bpcol = nb >> 12;
  const int tx7 = tcol & 7;
  float bias[4];
#pragma unroll
  for (int j = 0; j < 4; ++j) bias[j] = b2g[j * 16 + lr];  // true h = j*16+lr
#pragma unroll
  for (int j = 0; j < 4; ++j) {
    const int h = j * 16 + lr;
    const int hsw = (((h >> 3) ^ tx7) << 3) | (h & 7);
    const size_t colb = (size_t)bpcol * 4096 + tcol * 64 + hsw;
#pragma unroll
    for (int i = 0; i < 4; ++i) {
      const int u0r = m0 + wm * 64 + i * 16 + quad * 4;
#pragma unroll
      for (int r = 0; r < 4; ++r) {
        const float vv = fmaxf(acc[i][j][r] + bias[j], 0.f);
        C[(size_t)(u0r + r) * Nc + colb] = f2bf(vv);
      }
    }
  }
}

// ---------------------------------------------------------------------------
// K3 (MFMA): grid (NN) x 4 waves. Block stages W slab (24KB, pre-swizzled)
// into LDS once; each wave loops bp (= w + 4*it) with a private 8KB H2 slab.
// A-frags from LDS (2-way conflicts = free), conv = 3 shifted K=64 GEMMs,
// fused bias+relu+FC in-wave reduce. No spills (VGPR ~135).
// ---------------------------------------------------------------------------
__global__ __launch_bounds__(256, 2) void k3_tcn(const u16* __restrict__ H2,
                                                 const u16* __restrict__ Wb,
                                                 const float* __restrict__ tbg,
                                                 const float* __restrict__ fwg,
                                                 const float* __restrict__ fbg,
                                                 float* __restrict__ outg,
                                                 int b0, int Nc, int CBcur) {
  __shared__ __align__(16) char wlds[24576];
  __shared__ __align__(16) char hlds[4][8192];
  const int tid = threadIdx.x;
  const int n = blockIdx.x;
  const int w = tid >> 6, l = tid & 63;
  const int quad = l >> 4, lr = l & 15;
  const u16* Wp = Wb + (size_t)n * 12288;
  // cooperative W staging: wave w, chunk c -> bytes (c*4+w)*1024
#pragma unroll
  for (int c = 0; c < 6; ++c)
    gld_lds16(Wp + (c * 4 + w) * 512 + (size_t)l * 8, wlds + (c * 4 + w) * 1024);
  float tbv[4][4];
#pragma unroll
  for (int i = 0; i < 4; ++i)
#pragma unroll
    for (int r = 0; r < 4; ++r) tbv[i][r] = tbg[n * 64 + i * 16 + quad * 4 + r];
  const float fcb = fbg[0];
  bf16x8 bz;
#pragma unroll
  for (int jj = 0; jj < 8; ++jj) bz[jj] = 0;
  asm volatile("s_waitcnt vmcnt(0)" ::: "memory");
  __syncthreads();
  char* myl = hlds[w];
  const int lx7 = lr & 7;
  const f32x4 zz = {0.f, 0.f, 0.f, 0.f};
  for (int bp = w; bp < CBcur; bp += 4) {
    const u16* Hs = H2 + (size_t)n * Nc + bp * 4096;
    // all prior ds_reads of my slab consumed before overwrite (wave-local)
    asm volatile("s_waitcnt lgkmcnt(0)" ::: "memory");
#pragma unroll
    for (int c = 0; c < 8; ++c)
      gld_lds16(Hs + c * 512 + (size_t)l * 8, myl + c * 1024);
    asm volatile("s_waitcnt vmcnt(0)" ::: "memory");
    f32x4 acc[4][4];
#pragma unroll
    for (int i = 0; i < 4; ++i)
#pragma unroll
      for (int j = 0; j < 4; ++j) acc[i][j] = zz;
#pragma unroll
    for (int ks = 0; ks < 2; ++ks)
#pragma unroll
      for (int kk = 0; kk < 3; ++kk) {
        const int usw = ((ks * 4 + quad) ^ lx7) << 4;
        bf16x8 afr[4], bfr[4];
#pragma unroll
        for (int i = 0; i < 4; ++i)
          afr[i] = *(const bf16x8*)(wlds + kk * 8192 + (i * 16 + lr) * 128 + usw);
#pragma unroll
        for (int j = 0; j < 4; ++j) {
          const int tau = j * 16 + lr + kk - 1;
          const int tc = min(max(tau, 0), 63);
          const int off = tc * 128 + (((ks * 4 + quad) ^ (tc & 7)) << 4);
          const bf16x8 v = *(const bf16x8*)(myl + off);
          bfr[j] = (tau == tc) ? v : bz;
        }
#pragma unroll
        for (int i = 0; i < 4; ++i)
#pragma unroll
          for (int j = 0; j < 4; ++j)
            acc[i][j] = __builtin_amdgcn_mfma_f32_16x16x32_bf16(afr[i], bfr[j],
                                                                acc[i][j], 0, 0, 0);
      }
    // epilogue: bias + relu + FC dot, all in-wave
    float part = 0.f;
#pragma unroll
    for (int i = 0; i < 4; ++i)
#pragma unroll
      for (int r = 0; r < 4; ++r) {
        const int ho = i * 16 + quad * 4 + r;
        const float* fwp = fwg + ho * 64 + lr;
#pragma unroll
        for (int j = 0; j < 4; ++j)
          part += fmaxf(acc[i][j][r] + tbv[i][r], 0.f) * fwp[j * 16];
      }
#pragma unroll
    for (int off = 32; off > 0; off >>= 1) part += __shfl_xor(part, off, 64);
    if (l == 0) outg[(size_t)(b0 + bp) * NN + n] = part + fcb;
  }
}

// ---------------------------------------------------------------------------
extern "C" void kernel_launch(void* const* d_in, const int* in_sizes, int n_in,
                              void* d_out, int out_size, void* d_ws, size_t ws_size,
                              hipStream_t stream) {
  const float* xg   = (const float*)d_in[0];
  const float* adjg = (const float*)d_in[1];
  const float* w1g  = (const float*)d_in[2];
  const float* b1g  = (const float*)d_in[3];
  const float* w2g  = (const float*)d_in[4];
  const float* b2g  = (const float*)d_in[5];
  const float* twg  = (const float*)d_in[6];
  const float* tbg  = (const float*)d_in[7];
  const float* fwg  = (const float*)d_in[8];
  const float* fbg  = (const float*)d_in[9];
  float* outg = (float*)d_out;

  char* ws = (char*)d_ws;
  float* Sg = (float*)ws;                      // 4,194,304 B
  u16* adjb = (u16*)(ws + 4194304);            //   524,288 B
  u16* w2t  = (u16*)(ws + 4718592);            //     8,192 B (4KB used)
  u16* Wb   = (u16*)(ws + 4726784);            // 12,582,912 B
  const size_t fixedB = 17309696;
  int CB = 32;
  while (CB > 1 && fixedB + (size_t)CB * 8388608ull > ws_size) CB >>= 1;
  u16* Gg  = (u16*)(ws + fixedB);
  u16* H2g = Gg + (size_t)CB * 2097152;  // CB*4096 rows x 512
  const int Nc = CB * 4096;

  kcvt_adj<<<1024, 256, 0, stream>>>(adjg, adjb);
  kcvt_w2t<<<8, 256, 0, stream>>>(w2g, w2t);
  kcvt_w<<<24576, 256, 0, stream>>>(twg, Wb);
  k0_s<<<dim3(BB * TT / 64, NN / 64), 256, 0, stream>>>(xg, adjg, Sg);
  for (int b0 = 0; b0 < BB; b0 += CB) {
    k1_g<<<dim3(TT, CB), 256, 0, stream>>>(Sg, w1g, b1g, w2t, Gg, b0);
    k2_gemm<<<dim3(Nc / 128, 4), 256, 0, stream>>>(adjb, Gg, b2g, H2g, Nc);
    k3_tcn<<<dim3(NN), 256, 0, stream>>>(H2g, Wb, tbg, fwg, fbg, outg, b0, Nc, CB);
  }
}

// Round 8
// 323.100 us; speedup vs baseline: 1.4250x; 1.0970x over previous
//
#include <hip/hip_runtime.h>
#include <hip/hip_bf16.h>

#define BB 32
#define TT 64
#define NN 512
#define HH 64

using u16 = unsigned short;
using u32 = unsigned int;
typedef __attribute__((ext_vector_type(8))) short bf16x8;
typedef __attribute__((ext_vector_type(4))) float f32x4;

__device__ __forceinline__ float bf2f(u16 u) {
  union { u32 i; float f; } v; v.i = ((u32)u) << 16; return v.f;
}
__device__ __forceinline__ u16 f2bf(float f) {
  __hip_bfloat16 h = __float2bfloat16(f);
  u16 u; __builtin_memcpy(&u, &h, 2); return u;
}
// round-to-nearest-even bf16 (finite inputs only — identical to HW RNE)
__device__ __forceinline__ u16 f2bf_rne(float f) {
  union { float f; u32 u; } v; v.f = f;
  return (u16)((v.u + 0x7fff + ((v.u >> 16) & 1)) >> 16);
}

// async global->LDS, 16B per lane; lds base wave-uniform, lane i lands at
// ldsbase + i*16; GLOBAL address is per-lane (must include lane term).
__device__ __forceinline__ void gld_lds16(const void* g, void* l) {
  __builtin_amdgcn_global_load_lds(
      (const __attribute__((address_space(1))) u32*)g,
      (__attribute__((address_space(3))) u32*)l, 16, 0, 0);
}

// ---------------------------------------------------------------------------
// conversion kernels (run once per call)
// ---------------------------------------------------------------------------
__global__ __launch_bounds__(256) void kcvt_adj(const float* __restrict__ a,
                                                u16* __restrict__ o) {
  const int i = blockIdx.x * 256 + threadIdx.x;  // 262144 total
  o[i] = f2bf(a[i]);
}
__global__ __launch_bounds__(256) void kcvt_w2t(const float* __restrict__ w2,
                                                u16* __restrict__ o) {
  const int i = blockIdx.x * 256 + threadIdx.x;  // 2048 total, o[h*32+c]
  const int h = i >> 5, c = i & 31;
  o[i] = f2bf(w2[c * 64 + h]);
}
// tcn_w [n][ho][hi][kk] (fp32) -> Wb [n][kk][ho][hi'] (bf16), 16B unit of hi
// XOR-swizzled by (ho&7) so K3's linear LDS staging is conflict-free.
__global__ __launch_bounds__(256) void kcvt_w(const float* __restrict__ tw,
                                              u16* __restrict__ o) {
  const int i = blockIdx.x * 256 + threadIdx.x;  // 6291456 total
  const int his = i & 63;
  const int ho = (i >> 6) & 63;
  const int r = i >> 12;  // n*3 + kk
  const int n = r / 3, kk = r - n * 3;
  const int hi = (((his >> 3) ^ (ho & 7)) << 3) | (his & 7);
  o[i] = f2bf(tw[(n * 64 + ho) * 192 + hi * 3 + kk]);
}

// ---------------------------------------------------------------------------
// K0: S[bt][u] = sum_v X[bt][v] * adj[u][v]   (fp32 VALU, 1.07 GF — cheap)
// ---------------------------------------------------------------------------
__global__ __launch_bounds__(256) void k0_s(const float* __restrict__ xg,
                                            const float* __restrict__ adjg,
                                            float* __restrict__ Sg) {
  __shared__ __align__(16) float XsT[64][68];
  __shared__ __align__(16) float AdjT[64][68];
  const int tid = threadIdx.x;
  const int bt0 = blockIdx.x * 64, u0 = blockIdx.y * 64;
  const int ty = tid >> 4, tx = tid & 15;
  const int r = tid >> 2, cb = (tid & 3) << 4;
  float acc[4][4] = {};
  for (int v0 = 0; v0 < NN; v0 += 64) {
    {
      const float4* p = (const float4*)(xg + (((size_t)(bt0 + r)) << 9) + v0 + cb);
#pragma unroll
      for (int q = 0; q < 4; ++q) {
        float4 v = p[q];
        XsT[cb + q * 4 + 0][r] = v.x; XsT[cb + q * 4 + 1][r] = v.y;
        XsT[cb + q * 4 + 2][r] = v.z; XsT[cb + q * 4 + 3][r] = v.w;
      }
      const float4* pa = (const float4*)(adjg + (((size_t)(u0 + r)) << 9) + v0 + cb);
#pragma unroll
      for (int q = 0; q < 4; ++q) {
        float4 v = pa[q];
        AdjT[cb + q * 4 + 0][r] = v.x; AdjT[cb + q * 4 + 1][r] = v.y;
        AdjT[cb + q * 4 + 2][r] = v.z; AdjT[cb + q * 4 + 3][r] = v.w;
      }
    }
    __syncthreads();
#pragma unroll 8
    for (int v = 0; v < 64; ++v) {
      const float4 av = *(const float4*)&XsT[v][ty * 4];
      const float4 bv = *(const float4*)&AdjT[v][tx * 4];
      const float a[4] = {av.x, av.y, av.z, av.w};
      const float b[4] = {bv.x, bv.y, bv.z, bv.w};
#pragma unroll
      for (int i = 0; i < 4; ++i)
#pragma unroll
        for (int j = 0; j < 4; ++j) acc[i][j] += a[i] * b[j];
    }
    __syncthreads();
  }
#pragma unroll
  for (int i = 0; i < 4; ++i) {
    float4 o = {acc[i][0], acc[i][1], acc[i][2], acc[i][3]};
    *(float4*)&Sg[((size_t)(bt0 + ty * 4 + i)) * NN + u0 + tx * 4] = o;
  }
}

// ---------------------------------------------------------------------------
// K2 fused (K1+K2): C[u][n] = relu(sum_v adj[u][v] * G[n][v] + b2), where
// G[n=(bp,t,h)][v] = sum_c relu(w1[c]*S[b,t,v]+b1[c])*w2[c][h] is built
// IN-LDS per kt-step via small MFMAs (A from S in-reg, B = w2t reg-resident).
// No G tensor in HBM. Main loop & swizzled H2 epilogue identical to R7 k2.
// grid (tm=4, tn=Nc/128), 256 threads, 2x2 waves.
// ---------------------------------------------------------------------------
__global__ __launch_bounds__(256) void k2_fused(
    const u16* __restrict__ A, const float* __restrict__ Sg,
    const float* __restrict__ w1g, const float* __restrict__ b1g,
    const u16* __restrict__ w2t, const float* __restrict__ b2g,
    u16* __restrict__ C, int Nc, int b0) {
  __shared__ __align__(16) char smem[32768];  // As 16KB | Bs 16KB
  const int tid = threadIdx.x;
  const int w = tid >> 6, l = tid & 63;
  const int quad = l >> 4, lr = l & 15;
  const int tm = blockIdx.x, tn = blockIdx.y;
  const int m0 = tm * 128, n0 = tn * 128;
  const int wm = w >> 1, wn = w & 1;
  // A staging (adj): inst (w,c) covers rows c*32+w*8..+8, XOR-swizzled units
  const int rB = w * 8 + (l >> 3);
  const int uu = l & 7;
  const u16* agp[4];
#pragma unroll
  for (int c = 0; c < 4; ++c) {
    const int r = rB + c * 32;
    agp[c] = A + (size_t)(m0 + r) * 512 + ((uu ^ (r & 7)) * 8);
  }
  char* As = smem;
  char* Bs = smem + 16384;
  // panel roles: wave handles t_loc = w&1, vtiles {vtb, vtb+1}
  const int t_loc = w & 1, vtb = (w >> 1) << 1;
  const int t = ((n0 >> 6) + t_loc) & 63;
  const int bp = n0 >> 12;
  const size_t sRow = ((size_t)((b0 + bp) * 64 + t)) << 9;
  float w1v[8], b1v[8];
#pragma unroll
  for (int j = 0; j < 8; ++j) { w1v[j] = w1g[quad * 8 + j]; b1v[j] = b1g[quad * 8 + j]; }
  bf16x8 wf[4];
#pragma unroll
  for (int ht = 0; ht < 4; ++ht)
    wf[ht] = *(const bf16x8*)(w2t + (ht * 16 + lr) * 32 + quad * 8);
  int arow[4], brow[4];
#pragma unroll
  for (int i = 0; i < 4; ++i) {
    arow[i] = (wm * 64 + i * 16 + lr) * 128;
    brow[i] = (wn * 64 + i * 16 + lr) * 128;
  }
  const f32x4 zz = {0.f, 0.f, 0.f, 0.f};
  f32x4 acc[4][4];
#pragma unroll
  for (int i = 0; i < 4; ++i)
#pragma unroll
    for (int j = 0; j < 4; ++j) acc[i][j] = zz;
  const int lx7 = lr & 7;
  for (int kt = 0; kt < 8; ++kt) {
#pragma unroll
    for (int c = 0; c < 4; ++c)
      gld_lds16(agp[c] + kt * 64, As + (c * 32 + w * 8) * 128);
    // build B panel: G[row=t_loc*64+h][v-chunk] via MFMA, ds_write_b64
#pragma unroll
    for (int vi = 0; vi < 2; ++vi) {
      const int vt = vtb + vi;
      const float sv = Sg[sRow + kt * 64 + vt * 16 + lr];
      bf16x8 afS;
#pragma unroll
      for (int jj = 0; jj < 8; ++jj)
        afS[jj] = (short)f2bf_rne(fmaxf(fmaf(w1v[jj], sv, b1v[jj]), 0.f));
      const int qv = vt * 2 + (quad >> 1);
      const int bofs = ((qv ^ lx7) << 4) + ((quad & 1) << 3);
#pragma unroll
      for (int ht = 0; ht < 4; ++ht) {
        f32x4 p = __builtin_amdgcn_mfma_f32_16x16x32_bf16(afS, wf[ht], zz, 0, 0, 0);
        uint2 st;
        st.x = (u32)f2bf_rne(p[0]) | ((u32)f2bf_rne(p[1]) << 16);
        st.y = (u32)f2bf_rne(p[2]) | ((u32)f2bf_rne(p[3]) << 16);
        const int row = t_loc * 64 + ht * 16 + lr;
        *(uint2*)(Bs + row * 128 + bofs) = st;
      }
    }
    __syncthreads();
#pragma unroll
    for (int ks = 0; ks < 2; ++ks) {
      const int coff = (((ks * 4 + quad) ^ lx7)) * 16;
      bf16x8 afr[4], bfr[4];
#pragma unroll
      for (int i = 0; i < 4; ++i) afr[i] = *(const bf16x8*)(As + arow[i] + coff);
#pragma unroll
      for (int j = 0; j < 4; ++j) bfr[j] = *(const bf16x8*)(Bs + brow[j] + coff);
#pragma unroll
      for (int i = 0; i < 4; ++i)
#pragma unroll
        for (int j = 0; j < 4; ++j)
          acc[i][j] = __builtin_amdgcn_mfma_f32_16x16x32_bf16(afr[i], bfr[j], acc[i][j], 0, 0, 0);
    }
    __syncthreads();
  }
  // epilogue: bias+relu, write with per-(t)-row XOR swizzle on 16B units
  const int nb = n0 + wn * 64;
  const int tcol = (nb >> 6) & 63;
  const int bpcol = nb >> 12;
  const int tx7 = tcol & 7;
  float bias[4];
#pragma unroll
  for (int j = 0; j < 4; ++j) bias[j] = b2g[j * 16 + lr];  // true h = j*16+lr
#pragma unroll
  for (int j = 0; j < 4; ++j) {
    const int h = j * 16 + lr;
    const int hsw = (((h >> 3) ^ tx7) << 3) | (h & 7);
    const size_t colb = (size_t)bpcol * 4096 + tcol * 64 + hsw;
#pragma unroll
    for (int i = 0; i < 4; ++i) {
      const int u0r = m0 + wm * 64 + i * 16 + quad * 4;
#pragma unroll
      for (int r = 0; r < 4; ++r) {
        const float vv = fmaxf(acc[i][j][r] + bias[j], 0.f);
        C[(size_t)(u0r + r) * Nc + colb] = f2bf(vv);
      }
    }
  }
}

// ---------------------------------------------------------------------------
// K3 (MFMA): grid (NN) x 4 waves. Block stages W slab (24KB, pre-swizzled)
// into LDS once; each wave loops bp (= w + 4*it) with a private 8KB H2 slab.
// conv = 3 shifted K=64 GEMMs, fused bias+relu+FC in-wave reduce.
// ---------------------------------------------------------------------------
__global__ __launch_bounds__(256, 2) void k3_tcn(const u16* __restrict__ H2,
                                                 const u16* __restrict__ Wb,
                                                 const float* __restrict__ tbg,
                                                 const float* __restrict__ fwg,
                                                 const float* __restrict__ fbg,
                                                 float* __restrict__ outg,
                                                 int b0, int Nc, int CBcur) {
  __shared__ __align__(16) char wlds[24576];
  __shared__ __align__(16) char hlds[4][8192];
  const int tid = threadIdx.x;
  const int n = blockIdx.x;
  const int w = tid >> 6, l = tid & 63;
  const int quad = l >> 4, lr = l & 15;
  const u16* Wp = Wb + (size_t)n * 12288;
#pragma unroll
  for (int c = 0; c < 6; ++c)
    gld_lds16(Wp + (c * 4 + w) * 512 + (size_t)l * 8, wlds + (c * 4 + w) * 1024);
  float tbv[4][4];
#pragma unroll
  for (int i = 0; i < 4; ++i)
#pragma unroll
    for (int r = 0; r < 4; ++r) tbv[i][r] = tbg[n * 64 + i * 16 + quad * 4 + r];
  const float fcb = fbg[0];
  bf16x8 bz;
#pragma unroll
  for (int jj = 0; jj < 8; ++jj) bz[jj] = 0;
  asm volatile("s_waitcnt vmcnt(0)" ::: "memory");
  __syncthreads();
  char* myl = hlds[w];
  const int lx7 = lr & 7;
  const f32x4 zz = {0.f, 0.f, 0.f, 0.f};
  for (int bp = w; bp < CBcur; bp += 4) {
    const u16* Hs = H2 + (size_t)n * Nc + bp * 4096;
    asm volatile("s_waitcnt lgkmcnt(0)" ::: "memory");
#pragma unroll
    for (int c = 0; c < 8; ++c)
      gld_lds16(Hs + c * 512 + (size_t)l * 8, myl + c * 1024);
    asm volatile("s_waitcnt vmcnt(0)" ::: "memory");
    f32x4 acc[4][4];
#pragma unroll
    for (int i = 0; i < 4; ++i)
#pragma unroll
      for (int j = 0; j < 4; ++j) acc[i][j] = zz;
#pragma unroll
    for (int ks = 0; ks < 2; ++ks)
#pragma unroll
      for (int kk = 0; kk < 3; ++kk) {
        const int usw = ((ks * 4 + quad) ^ lx7) << 4;
        bf16x8 afr[4], bfr[4];
#pragma unroll
        for (int i = 0; i < 4; ++i)
          afr[i] = *(const bf16x8*)(wlds + kk * 8192 + (i * 16 + lr) * 128 + usw);
#pragma unroll
        for (int j = 0; j < 4; ++j) {
          const int tau = j * 16 + lr + kk - 1;
          const int tc = min(max(tau, 0), 63);
          const int off = tc * 128 + (((ks * 4 + quad) ^ (tc & 7)) << 4);
          const bf16x8 v = *(const bf16x8*)(myl + off);
          bfr[j] = (tau == tc) ? v : bz;
        }
#pragma unroll
        for (int i = 0; i < 4; ++i)
#pragma unroll
          for (int j = 0; j < 4; ++j)
            acc[i][j] = __builtin_amdgcn_mfma_f32_16x16x32_bf16(afr[i], bfr[j],
                                                                acc[i][j], 0, 0, 0);
      }
    float part = 0.f;
#pragma unroll
    for (int i = 0; i < 4; ++i)
#pragma unroll
      for (int r = 0; r < 4; ++r) {
        const int ho = i * 16 + quad * 4 + r;
        const float* fwp = fwg + ho * 64 + lr;
#pragma unroll
        for (int j = 0; j < 4; ++j)
          part += fmaxf(acc[i][j][r] + tbv[i][r], 0.f) * fwp[j * 16];
      }
#pragma unroll
    for (int off = 32; off > 0; off >>= 1) part += __shfl_xor(part, off, 64);
    if (l == 0) outg[(size_t)(b0 + bp) * NN + n] = part + fcb;
  }
}

// ---------------------------------------------------------------------------
extern "C" void kernel_launch(void* const* d_in, const int* in_sizes, int n_in,
                              void* d_out, int out_size, void* d_ws, size_t ws_size,
                              hipStream_t stream) {
  const float* xg   = (const float*)d_in[0];
  const float* adjg = (const float*)d_in[1];
  const float* w1g  = (const float*)d_in[2];
  const float* b1g  = (const float*)d_in[3];
  const float* w2g  = (const float*)d_in[4];
  const float* b2g  = (const float*)d_in[5];
  const float* twg  = (const float*)d_in[6];
  const float* tbg  = (const float*)d_in[7];
  const float* fwg  = (const float*)d_in[8];
  const float* fbg  = (const float*)d_in[9];
  float* outg = (float*)d_out;

  char* ws = (char*)d_ws;
  float* Sg = (float*)ws;                      // 4,194,304 B
  u16* adjb = (u16*)(ws + 4194304);            //   524,288 B
  u16* w2t  = (u16*)(ws + 4718592);            //     8,192 B (4KB used)
  u16* Wb   = (u16*)(ws + 4726784);            // 12,582,912 B
  const size_t fixedB = 17309696;
  int CB = 32;
  while (CB > 1 && fixedB + (size_t)CB * 4194304ull > ws_size) CB >>= 1;
  u16* H2g = (u16*)(ws + fixedB);              // CB*4096 cols x 512 rows
  const int Nc = CB * 4096;

  kcvt_adj<<<1024, 256, 0, stream>>>(adjg, adjb);
  kcvt_w2t<<<8, 256, 0, stream>>>(w2g, w2t);
  kcvt_w<<<24576, 256, 0, stream>>>(twg, Wb);
  k0_s<<<dim3(BB * TT / 64, NN / 64), 256, 0, stream>>>(xg, adjg, Sg);
  for (int b0 = 0; b0 < BB; b0 += CB) {
    k2_fused<<<dim3(4, Nc / 128), 256, 0, stream>>>(adjb, Sg, w1g, b1g, w2t, b2g,
                                                    H2g, Nc, b0);
    k3_tcn<<<dim3(NN), 256, 0, stream>>>(H2g, Wb, tbg, fwg, fbg, outg, b0, Nc, CB);
  }
}

// Round 10
// 308.590 us; speedup vs baseline: 1.4920x; 1.0470x over previous
//
#include <hip/hip_runtime.h>
#include <hip/hip_bf16.h>

#define BB 32
#define TT 64
#define NN 512
#define HH 64

using u16 = unsigned short;
using u32 = unsigned int;
typedef _Float16 f16x8 __attribute__((ext_vector_type(8)));
typedef __fp16 fp16x2 __attribute__((ext_vector_type(2)));
typedef __attribute__((ext_vector_type(4))) float f32x4;

__device__ __forceinline__ u16 f2h_bits(float f) {
  _Float16 h = (_Float16)f;  // v_cvt_f16_f32, RNE, 1 instr
  u16 u; __builtin_memcpy(&u, &h, 2); return u;
}
__device__ __forceinline__ u32 pk2h(float a, float b) {  // v_cvt_pkrtz, 1 instr
  fp16x2 h = __builtin_amdgcn_cvt_pkrtz(a, b);
  u32 u; __builtin_memcpy(&u, &h, 4); return u;
}

// async global->LDS, 16B per lane; lds base wave-uniform, lane i lands at
// ldsbase + i*16; GLOBAL address is per-lane (must include lane term).
__device__ __forceinline__ void gld_lds16(const void* g, void* l) {
  __builtin_amdgcn_global_load_lds(
      (const __attribute__((address_space(1))) u32*)g,
      (__attribute__((address_space(3))) u32*)l, 16, 0, 0);
}

// ---------------------------------------------------------------------------
// conversion kernels (run once per call) — all outputs fp16 now
// ---------------------------------------------------------------------------
__global__ __launch_bounds__(256) void kcvt_adj(const float* __restrict__ a,
                                                u16* __restrict__ o) {
  const int i = blockIdx.x * 256 + threadIdx.x;  // 262144 total
  o[i] = f2h_bits(a[i]);
}
__global__ __launch_bounds__(256) void kcvt_w2t(const float* __restrict__ w2,
                                                u16* __restrict__ o) {
  const int i = blockIdx.x * 256 + threadIdx.x;  // 2048 total, o[h*32+c]
  const int h = i >> 5, c = i & 31;
  o[i] = f2h_bits(w2[c * 64 + h]);
}
// tcn_w [n][ho][hi][kk] (fp32) -> Wb [n][kk][ho][hi'] (f16), 16B unit of hi
// XOR-swizzled by (ho&7) so K3's linear LDS staging is conflict-free.
__global__ __launch_bounds__(256) void kcvt_w(const float* __restrict__ tw,
                                              u16* __restrict__ o) {
  const int i = blockIdx.x * 256 + threadIdx.x;  // 6291456 total
  const int his = i & 63;
  const int ho = (i >> 6) & 63;
  const int r = i >> 12;  // n*3 + kk
  const int n = r / 3, kk = r - n * 3;
  const int hi = (((his >> 3) ^ (ho & 7)) << 3) | (his & 7);
  o[i] = f2h_bits(tw[(n * 64 + ho) * 192 + hi * 3 + kk]);
}

// ---------------------------------------------------------------------------
// K0: S[bt][u] = sum_v X[bt][v] * adj[u][v]   (fp32 VALU, 1.07 GF — cheap)
// ---------------------------------------------------------------------------
__global__ __launch_bounds__(256) void k0_s(const float* __restrict__ xg,
                                            const float* __restrict__ adjg,
                                            float* __restrict__ Sg) {
  __shared__ __align__(16) float XsT[64][68];
  __shared__ __align__(16) float AdjT[64][68];
  const int tid = threadIdx.x;
  const int bt0 = blockIdx.x * 64, u0 = blockIdx.y * 64;
  const int ty = tid >> 4, tx = tid & 15;
  const int r = tid >> 2, cb = (tid & 3) << 4;
  float acc[4][4] = {};
  for (int v0 = 0; v0 < NN; v0 += 64) {
    {
      const float4* p = (const float4*)(xg + (((size_t)(bt0 + r)) << 9) + v0 + cb);
#pragma unroll
      for (int q = 0; q < 4; ++q) {
        float4 v = p[q];
        XsT[cb + q * 4 + 0][r] = v.x; XsT[cb + q * 4 + 1][r] = v.y;
        XsT[cb + q * 4 + 2][r] = v.z; XsT[cb + q * 4 + 3][r] = v.w;
      }
      const float4* pa = (const float4*)(adjg + (((size_t)(u0 + r)) << 9) + v0 + cb);
#pragma unroll
      for (int q = 0; q < 4; ++q) {
        float4 v = pa[q];
        AdjT[cb + q * 4 + 0][r] = v.x; AdjT[cb + q * 4 + 1][r] = v.y;
        AdjT[cb + q * 4 + 2][r] = v.z; AdjT[cb + q * 4 + 3][r] = v.w;
      }
    }
    __syncthreads();
#pragma unroll 8
    for (int v = 0; v < 64; ++v) {
      const float4 av = *(const float4*)&XsT[v][ty * 4];
      const float4 bv = *(const float4*)&AdjT[v][tx * 4];
      const float a[4] = {av.x, av.y, av.z, av.w};
      const float b[4] = {bv.x, bv.y, bv.z, bv.w};
#pragma unroll
      for (int i = 0; i < 4; ++i)
#pragma unroll
        for (int j = 0; j < 4; ++j) acc[i][j] += a[i] * b[j];
    }
    __syncthreads();
  }
#pragma unroll
  for (int i = 0; i < 4; ++i) {
    float4 o = {acc[i][0], acc[i][1], acc[i][2], acc[i][3]};
    *(float4*)&Sg[((size_t)(bt0 + ty * 4 + i)) * NN + u0 + tx * 4] = o;
  }
}

// ---------------------------------------------------------------------------
// K2 fused (K1+K2), fp16: C[u][n] = relu(sum_v adj[u][v]*G[n][v] + b2), with
// G panel built in-LDS per kt via small MFMAs; HW f16 converts (cvt/pkrtz).
// grid (tm=4, tn=Nc/128), 256 threads, 2x2 waves.
// ---------------------------------------------------------------------------
__global__ __launch_bounds__(256) void k2_fused(
    const u16* __restrict__ A, const float* __restrict__ Sg,
    const float* __restrict__ w1g, const float* __restrict__ b1g,
    const u16* __restrict__ w2t, const float* __restrict__ b2g,
    u16* __restrict__ C, int Nc, int b0) {
  __shared__ __align__(16) char smem[32768];  // As 16KB | Bs 16KB
  const int tid = threadIdx.x;
  const int w = tid >> 6, l = tid & 63;
  const int quad = l >> 4, lr = l & 15;
  const int tm = blockIdx.x, tn = blockIdx.y;
  const int m0 = tm * 128, n0 = tn * 128;
  const int wm = w >> 1, wn = w & 1;
  const int rB = w * 8 + (l >> 3);
  const int uu = l & 7;
  const u16* agp[4];
#pragma unroll
  for (int c = 0; c < 4; ++c) {
    const int r = rB + c * 32;
    agp[c] = A + (size_t)(m0 + r) * 512 + ((uu ^ (r & 7)) * 8);
  }
  char* As = smem;
  char* Bs = smem + 16384;
  const int t_loc = w & 1, vtb = (w >> 1) << 1;
  const int t = ((n0 >> 6) + t_loc) & 63;
  const int bp = n0 >> 12;
  const size_t sRow = ((size_t)((b0 + bp) * 64 + t)) << 9;
  float w1v[8], b1v[8];
#pragma unroll
  for (int j = 0; j < 8; ++j) { w1v[j] = w1g[quad * 8 + j]; b1v[j] = b1g[quad * 8 + j]; }
  f16x8 wf[4];
#pragma unroll
  for (int ht = 0; ht < 4; ++ht)
    wf[ht] = *(const f16x8*)(w2t + (ht * 16 + lr) * 32 + quad * 8);
  int arow[4], brow[4];
#pragma unroll
  for (int i = 0; i < 4; ++i) {
    arow[i] = (wm * 64 + i * 16 + lr) * 128;
    brow[i] = (wn * 64 + i * 16 + lr) * 128;
  }
  const f32x4 zz = {0.f, 0.f, 0.f, 0.f};
  f32x4 acc[4][4];
#pragma unroll
  for (int i = 0; i < 4; ++i)
#pragma unroll
    for (int j = 0; j < 4; ++j) acc[i][j] = zz;
  const int lx7 = lr & 7;
  for (int kt = 0; kt < 8; ++kt) {
#pragma unroll
    for (int c = 0; c < 4; ++c)
      gld_lds16(agp[c] + kt * 64, As + (c * 32 + w * 8) * 128);
    // build B panel: G[row=t_loc*64+h][v-chunk] via MFMA, ds_write_b64
#pragma unroll
    for (int vi = 0; vi < 2; ++vi) {
      const int vt = vtb + vi;
      const float sv = Sg[sRow + kt * 64 + vt * 16 + lr];
      f16x8 afS;
#pragma unroll
      for (int jj = 0; jj < 8; ++jj)
        afS[jj] = (_Float16)(fmaxf(fmaf(w1v[jj], sv, b1v[jj]), 0.f));
      const int qv = vt * 2 + (quad >> 1);
      const int bofs = ((qv ^ lx7) << 4) + ((quad & 1) << 3);
#pragma unroll
      for (int ht = 0; ht < 4; ++ht) {
        f32x4 p = __builtin_amdgcn_mfma_f32_16x16x32_f16(afS, wf[ht], zz, 0, 0, 0);
        uint2 st;
        st.x = pk2h(p[0], p[1]);
        st.y = pk2h(p[2], p[3]);
        const int row = t_loc * 64 + ht * 16 + lr;
        *(uint2*)(Bs + row * 128 + bofs) = st;
      }
    }
    __syncthreads();
#pragma unroll
    for (int ks = 0; ks < 2; ++ks) {
      const int coff = (((ks * 4 + quad) ^ lx7)) * 16;
      f16x8 afr[4], bfr[4];
#pragma unroll
      for (int i = 0; i < 4; ++i) afr[i] = *(const f16x8*)(As + arow[i] + coff);
#pragma unroll
      for (int j = 0; j < 4; ++j) bfr[j] = *(const f16x8*)(Bs + brow[j] + coff);
#pragma unroll
      for (int i = 0; i < 4; ++i)
#pragma unroll
        for (int j = 0; j < 4; ++j)
          acc[i][j] = __builtin_amdgcn_mfma_f32_16x16x32_f16(afr[i], bfr[j], acc[i][j], 0, 0, 0);
    }
    __syncthreads();
  }
  // epilogue: bias+relu, write with per-(t)-row XOR swizzle on 16B units
  const int nb = n0 + wn * 64;
  const int tcol = (nb >> 6) & 63;
  const int bpcol = nb >> 12;
  const int tx7 = tcol & 7;
  float bias[4];
#pragma unroll
  for (int j = 0; j < 4; ++j) bias[j] = b2g[j * 16 + lr];  // true h = j*16+lr
#pragma unroll
  for (int j = 0; j < 4; ++j) {
    const int h = j * 16 + lr;
    const int hsw = (((h >> 3) ^ tx7) << 3) | (h & 7);
    const size_t colb = (size_t)bpcol * 4096 + tcol * 64 + hsw;
#pragma unroll
    for (int i = 0; i < 4; ++i) {
      const int u0r = m0 + wm * 64 + i * 16 + quad * 4;
#pragma unroll
      for (int r = 0; r < 4; ++r) {
        const float vv = fmaxf(acc[i][j][r] + bias[j], 0.f);
        C[(size_t)(u0r + r) * Nc + colb] = f2h_bits(vv);
      }
    }
  }
}

// ---------------------------------------------------------------------------
// K3 (MFMA, fp16): grid (NN) x 4 waves. Block stages W slab (24KB,
// pre-swizzled) into LDS once; each wave loops bp (= w + 4*it) with a
// private 8KB H2 slab. conv = 3 shifted K=64 GEMMs, fused bias+relu+FC.
// ---------------------------------------------------------------------------
__global__ __launch_bounds__(256, 2) void k3_tcn(const u16* __restrict__ H2,
                                                 const u16* __restrict__ Wb,
                                                 const float* __restrict__ tbg,
                                                 const float* __restrict__ fwg,
                                                 const float* __restrict__ fbg,
                                                 float* __restrict__ outg,
                                                 int b0, int Nc, int CBcur) {
  __shared__ __align__(16) char wlds[24576];
  __shared__ __align__(16) char hlds[4][8192];
  const int tid = threadIdx.x;
  const int n = blockIdx.x;
  const int w = tid >> 6, l = tid & 63;
  const int quad = l >> 4, lr = l & 15;
  const u16* Wp = Wb + (size_t)n * 12288;
#pragma unroll
  for (int c = 0; c < 6; ++c)
    gld_lds16(Wp + (c * 4 + w) * 512 + (size_t)l * 8, wlds + (c * 4 + w) * 1024);
  float tbv[4][4];
#pragma unroll
  for (int i = 0; i < 4; ++i)
#pragma unroll
    for (int r = 0; r < 4; ++r) tbv[i][r] = tbg[n * 64 + i * 16 + quad * 4 + r];
  const float fcb = fbg[0];
  f16x8 bz;
#pragma unroll
  for (int jj = 0; jj < 8; ++jj) bz[jj] = (_Float16)0.f;
  asm volatile("s_waitcnt vmcnt(0)" ::: "memory");
  __syncthreads();
  char* myl = hlds[w];
  const int lx7 = lr & 7;
  const f32x4 zz = {0.f, 0.f, 0.f, 0.f};
  for (int bp = w; bp < CBcur; bp += 4) {
    const u16* Hs = H2 + (size_t)n * Nc + bp * 4096;
    asm volatile("s_waitcnt lgkmcnt(0)" ::: "memory");
#pragma unroll
    for (int c = 0; c < 8; ++c)
      gld_lds16(Hs + c * 512 + (size_t)l * 8, myl + c * 1024);
    asm volatile("s_waitcnt vmcnt(0)" ::: "memory");
    f32x4 acc[4][4];
#pragma unroll
    for (int i = 0; i < 4; ++i)
#pragma unroll
      for (int j = 0; j < 4; ++j) acc[i][j] = zz;
#pragma unroll
    for (int ks = 0; ks < 2; ++ks)
#pragma unroll
      for (int kk = 0; kk < 3; ++kk) {
        const int usw = ((ks * 4 + quad) ^ lx7) << 4;
        f16x8 afr[4], bfr[4];
#pragma unroll
        for (int i = 0; i < 4; ++i)
          afr[i] = *(const f16x8*)(wlds + kk * 8192 + (i * 16 + lr) * 128 + usw);
#pragma unroll
        for (int j = 0; j < 4; ++j) {
          const int tau = j * 16 + lr + kk - 1;
          const int tc = min(max(tau, 0), 63);
          const int off = tc * 128 + (((ks * 4 + quad) ^ (tc & 7)) << 4);
          const f16x8 v = *(const f16x8*)(myl + off);
          bfr[j] = (tau == tc) ? v : bz;
        }
#pragma unroll
        for (int i = 0; i < 4; ++i)
#pragma unroll
          for (int j = 0; j < 4; ++j)
            acc[i][j] = __builtin_amdgcn_mfma_f32_16x16x32_f16(afr[i], bfr[j],
                                                               acc[i][j], 0, 0, 0);
      }
    float part = 0.f;
#pragma unroll
    for (int i = 0; i < 4; ++i)
#pragma unroll
      for (int r = 0; r < 4; ++r) {
        const int ho = i * 16 + quad * 4 + r;
        const float* fwp = fwg + ho * 64 + lr;
#pragma unroll
        for (int j = 0; j < 4; ++j)
          part += fmaxf(acc[i][j][r] + tbv[i][r], 0.f) * fwp[j * 16];
      }
#pragma unroll
    for (int off = 32; off > 0; off >>= 1) part += __shfl_xor(part, off, 64);
    if (l == 0) outg[(size_t)(b0 + bp) * NN + n] = part + fcb;
  }
}

// ---------------------------------------------------------------------------
extern "C" void kernel_launch(void* const* d_in, const int* in_sizes, int n_in,
                              void* d_out, int out_size, void* d_ws, size_t ws_size,
                              hipStream_t stream) {
  const float* xg   = (const float*)d_in[0];
  const float* adjg = (const float*)d_in[1];
  const float* w1g  = (const float*)d_in[2];
  const float* b1g  = (const float*)d_in[3];
  const float* w2g  = (const float*)d_in[4];
  const float* b2g  = (const float*)d_in[5];
  const float* twg  = (const float*)d_in[6];
  const float* tbg  = (const float*)d_in[7];
  const float* fwg  = (const float*)d_in[8];
  const float* fbg  = (const float*)d_in[9];
  float* outg = (float*)d_out;

  char* ws = (char*)d_ws;
  float* Sg = (float*)ws;                      // 4,194,304 B
  u16* adjb = (u16*)(ws + 4194304);            //   524,288 B
  u16* w2t  = (u16*)(ws + 4718592);            //     8,192 B (4KB used)
  u16* Wb   = (u16*)(ws + 4726784);            // 12,582,912 B
  const size_t fixedB = 17309696;
  int CB = 32;
  while (CB > 1 && fixedB + (size_t)CB * 4194304ull > ws_size) CB >>= 1;
  u16* H2g = (u16*)(ws + fixedB);              // CB*4096 cols x 512 rows
  const int Nc = CB * 4096;

  kcvt_adj<<<1024, 256, 0, stream>>>(adjg, adjb);
  kcvt_w2t<<<8, 256, 0, stream>>>(w2g, w2t);
  kcvt_w<<<24576, 256, 0, stream>>>(twg, Wb);
  k0_s<<<dim3(BB * TT / 64, NN / 64), 256, 0, stream>>>(xg, adjg, Sg);
  for (int b0 = 0; b0 < BB; b0 += CB) {
    k2_fused<<<dim3(4, Nc / 128), 256, 0, stream>>>(adjb, Sg, w1g, b1g, w2t, b2g,
                                                    H2g, Nc, b0);
    k3_tcn<<<dim3(NN), 256, 0, stream>>>(H2g, Wb, tbg, fwg, fbg, outg, b0, Nc, CB);
  }
}

// Round 12
// 280.739 us; speedup vs baseline: 1.6400x; 1.0992x over previous
//
#include <hip/hip_runtime.h>
#include <hip/hip_bf16.h>

#define BB 32
#define TT 64
#define NN 512
#define HH 64

using u16 = unsigned short;
using u32 = unsigned int;
typedef _Float16 f16x8 __attribute__((ext_vector_type(8)));
typedef __fp16 fp16x2 __attribute__((ext_vector_type(2)));
typedef __attribute__((ext_vector_type(4))) float f32x4;

__device__ __forceinline__ u16 f2h_bits(float f) {
  _Float16 h = (_Float16)f;  // v_cvt_f16_f32, RNE, 1 instr
  u16 u; __builtin_memcpy(&u, &h, 2); return u;
}
__device__ __forceinline__ u32 pk2h(float a, float b) {  // v_cvt_pkrtz, 1 instr
  fp16x2 h = __builtin_amdgcn_cvt_pkrtz(a, b);
  u32 u; __builtin_memcpy(&u, &h, 4); return u;
}

// async global->LDS, 16B per lane; lds base wave-uniform, lane i lands at
// ldsbase + i*16; GLOBAL address is per-lane (must include lane term).
__device__ __forceinline__ void gld_lds16(const void* g, void* l) {
  __builtin_amdgcn_global_load_lds(
      (const __attribute__((address_space(1))) u32*)g,
      (__attribute__((address_space(3))) u32*)l, 16, 0, 0);
}

// ---------------------------------------------------------------------------
// conversion kernels (run once per call) — all outputs fp16
// ---------------------------------------------------------------------------
__global__ __launch_bounds__(256) void kcvt_adj(const float* __restrict__ a,
                                                u16* __restrict__ o) {
  const int i = blockIdx.x * 256 + threadIdx.x;  // 262144 total
  o[i] = f2h_bits(a[i]);
}
__global__ __launch_bounds__(256) void kcvt_w2t(const float* __restrict__ w2,
                                                u16* __restrict__ o) {
  const int i = blockIdx.x * 256 + threadIdx.x;  // 2048 total, o[h*32+c]
  const int h = i >> 5, c = i & 31;
  o[i] = f2h_bits(w2[c * 64 + h]);
}
// tcn_w [n][ho][hi][kk] (fp32) -> Wb [n][kk][ho][hi'] (f16), 16B unit of hi
// XOR-swizzled by (ho&7) so K3's linear LDS staging is conflict-free.
__global__ __launch_bounds__(256) void kcvt_w(const float* __restrict__ tw,
                                              u16* __restrict__ o) {
  const int i = blockIdx.x * 256 + threadIdx.x;  // 6291456 total
  const int his = i & 63;
  const int ho = (i >> 6) & 63;
  const int r = i >> 12;  // n*3 + kk
  const int n = r / 3, kk = r - n * 3;
  const int hi = (((his >> 3) ^ (ho & 7)) << 3) | (his & 7);
  o[i] = f2h_bits(tw[(n * 64 + ho) * 192 + hi * 3 + kk]);
}

// ---------------------------------------------------------------------------
// K0: S[bt][u] = sum_v X[bt][v] * adj[u][v]   (fp32 VALU, 1.07 GF — cheap)
// ---------------------------------------------------------------------------
__global__ __launch_bounds__(256) void k0_s(const float* __restrict__ xg,
                                            const float* __restrict__ adjg,
                                            float* __restrict__ Sg) {
  __shared__ __align__(16) float XsT[64][68];
  __shared__ __align__(16) float AdjT[64][68];
  const int tid = threadIdx.x;
  const int bt0 = blockIdx.x * 64, u0 = blockIdx.y * 64;
  const int ty = tid >> 4, tx = tid & 15;
  const int r = tid >> 2, cb = (tid & 3) << 4;
  float acc[4][4] = {};
  for (int v0 = 0; v0 < NN; v0 += 64) {
    {
      const float4* p = (const float4*)(xg + (((size_t)(bt0 + r)) << 9) + v0 + cb);
#pragma unroll
      for (int q = 0; q < 4; ++q) {
        float4 v = p[q];
        XsT[cb + q * 4 + 0][r] = v.x; XsT[cb + q * 4 + 1][r] = v.y;
        XsT[cb + q * 4 + 2][r] = v.z; XsT[cb + q * 4 + 3][r] = v.w;
      }
      const float4* pa = (const float4*)(adjg + (((size_t)(u0 + r)) << 9) + v0 + cb);
#pragma unroll
      for (int q = 0; q < 4; ++q) {
        float4 v = pa[q];
        AdjT[cb + q * 4 + 0][r] = v.x; AdjT[cb + q * 4 + 1][r] = v.y;
        AdjT[cb + q * 4 + 2][r] = v.z; AdjT[cb + q * 4 + 3][r] = v.w;
      }
    }
    __syncthreads();
#pragma unroll 8
    for (int v = 0; v < 64; ++v) {
      const float4 av = *(const float4*)&XsT[v][ty * 4];
      const float4 bv = *(const float4*)&AdjT[v][tx * 4];
      const float a[4] = {av.x, av.y, av.z, av.w};
      const float b[4] = {bv.x, bv.y, bv.z, bv.w};
#pragma unroll
      for (int i = 0; i < 4; ++i)
#pragma unroll
        for (int j = 0; j < 4; ++j) acc[i][j] += a[i] * b[j];
    }
    __syncthreads();
  }
#pragma unroll
  for (int i = 0; i < 4; ++i) {
    float4 o = {acc[i][0], acc[i][1], acc[i][2], acc[i][3]};
    *(float4*)&Sg[((size_t)(bt0 + ty * 4 + i)) * NN + u0 + tx * 4] = o;
  }
}

// ---------------------------------------------------------------------------
// K2 fused (K1+K2), fp16: C[u][n] = relu(sum_v adj[u][v]*G[n][v] + b2), with
// G panel built in-LDS per kt via small MFMAs; phi frags via native _Float16
// vector math (clang -> v_pk_fma_f16 / v_pk_max_f16, ~8 ops/frag).
// grid (tm=4, tn=Nc/128), 256 threads, 2x2 waves.
// ---------------------------------------------------------------------------
__global__ __launch_bounds__(256) void k2_fused(
    const u16* __restrict__ A, const float* __restrict__ Sg,
    const float* __restrict__ w1g, const float* __restrict__ b1g,
    const u16* __restrict__ w2t, const float* __restrict__ b2g,
    u16* __restrict__ C, int Nc, int b0) {
  __shared__ __align__(16) char smem[32768];  // As 16KB | Bs 16KB
  const int tid = threadIdx.x;
  const int w = tid >> 6, l = tid & 63;
  const int quad = l >> 4, lr = l & 15;
  const int tm = blockIdx.x, tn = blockIdx.y;
  const int m0 = tm * 128, n0 = tn * 128;
  const int wm = w >> 1, wn = w & 1;
  const int rB = w * 8 + (l >> 3);
  const int uu = l & 7;
  const u16* agp[4];
#pragma unroll
  for (int c = 0; c < 4; ++c) {
    const int r = rB + c * 32;
    agp[c] = A + (size_t)(m0 + r) * 512 + ((uu ^ (r & 7)) * 8);
  }
  char* As = smem;
  char* Bs = smem + 16384;
  const int t_loc = w & 1, vtb = (w >> 1) << 1;
  const int t = ((n0 >> 6) + t_loc) & 63;
  const int bp = n0 >> 12;
  const size_t sRow = ((size_t)((b0 + bp) * 64 + t)) << 9;
  // f16 vector w1/b1 for the quad's 8 channels
  f16x8 w1h, b1h, zero8;
#pragma unroll
  for (int j = 0; j < 8; ++j) {
    w1h[j] = (_Float16)w1g[quad * 8 + j];
    b1h[j] = (_Float16)b1g[quad * 8 + j];
    zero8[j] = (_Float16)0.f;
  }
  f16x8 wf[4];
#pragma unroll
  for (int ht = 0; ht < 4; ++ht)
    wf[ht] = *(const f16x8*)(w2t + (ht * 16 + lr) * 32 + quad * 8);
  int arow[4], brow[4];
#pragma unroll
  for (int i = 0; i < 4; ++i) {
    arow[i] = (wm * 64 + i * 16 + lr) * 128;
    brow[i] = (wn * 64 + i * 16 + lr) * 128;
  }
  const f32x4 zz = {0.f, 0.f, 0.f, 0.f};
  f32x4 acc[4][4];
#pragma unroll
  for (int i = 0; i < 4; ++i)
#pragma unroll
    for (int j = 0; j < 4; ++j) acc[i][j] = zz;
  const int lx7 = lr & 7;
  for (int kt = 0; kt < 8; ++kt) {
#pragma unroll
    for (int c = 0; c < 4; ++c)
      gld_lds16(agp[c] + kt * 64, As + (c * 32 + w * 8) * 128);
    // build B panel: G[row=t_loc*64+h][v-chunk] via MFMA, ds_write_b64
#pragma unroll
    for (int vi = 0; vi < 2; ++vi) {
      const int vt = vtb + vi;
      const float sv = Sg[sRow + kt * 64 + vt * 16 + lr];
      const _Float16 svh = (_Float16)sv;
      f16x8 svp;
#pragma unroll
      for (int j = 0; j < 8; ++j) svp[j] = svh;
      f16x8 afS = __builtin_elementwise_max(w1h * svp + b1h, zero8);
      const int qv = vt * 2 + (quad >> 1);
      const int bofs = ((qv ^ lx7) << 4) + ((quad & 1) << 3);
#pragma unroll
      for (int ht = 0; ht < 4; ++ht) {
        f32x4 p = __builtin_amdgcn_mfma_f32_16x16x32_f16(afS, wf[ht], zz, 0, 0, 0);
        uint2 st;
        st.x = pk2h(p[0], p[1]);
        st.y = pk2h(p[2], p[3]);
        const int row = t_loc * 64 + ht * 16 + lr;
        *(uint2*)(Bs + row * 128 + bofs) = st;
      }
    }
    __syncthreads();
#pragma unroll
    for (int ks = 0; ks < 2; ++ks) {
      const int coff = (((ks * 4 + quad) ^ lx7)) * 16;
      f16x8 afr[4], bfr[4];
#pragma unroll
      for (int i = 0; i < 4; ++i) afr[i] = *(const f16x8*)(As + arow[i] + coff);
#pragma unroll
      for (int j = 0; j < 4; ++j) bfr[j] = *(const f16x8*)(Bs + brow[j] + coff);
#pragma unroll
      for (int i = 0; i < 4; ++i)
#pragma unroll
        for (int j = 0; j < 4; ++j)
          acc[i][j] = __builtin_amdgcn_mfma_f32_16x16x32_f16(afr[i], bfr[j], acc[i][j], 0, 0, 0);
    }
    __syncthreads();
  }
  // epilogue: bias+relu, write with per-(t)-row XOR swizzle on 16B units
  const int nb = n0 + wn * 64;
  const int tcol = (nb >> 6) & 63;
  const int bpcol = nb >> 12;
  const int tx7 = tcol & 7;
  float bias[4];
#pragma unroll
  for (int j = 0; j < 4; ++j) bias[j] = b2g[j * 16 + lr];  // true h = j*16+lr
#pragma unroll
  for (int j = 0; j < 4; ++j) {
    const int h = j * 16 + lr;
    const int hsw = (((h >> 3) ^ tx7) << 3) | (h & 7);
    const size_t colb = (size_t)bpcol * 4096 + tcol * 64 + hsw;
#pragma unroll
    for (int i = 0; i < 4; ++i) {
      const int u0r = m0 + wm * 64 + i * 16 + quad * 4;
#pragma unroll
      for (int r = 0; r < 4; ++r) {
        const float vv = fmaxf(acc[i][j][r] + bias[j], 0.f);
        C[(size_t)(u0r + r) * Nc + colb] = f2h_bits(vv);
      }
    }
  }
}

// ---------------------------------------------------------------------------
// K3 (MFMA, fp16, software-pipelined): grid (NN) x 4 waves. W slab (24KB,
// pre-swizzled) in LDS once per block. Wave loops bp (= w + 4*it): PREFETCH
// next slab into VGPRs before computing current from its private 8KB LDS
// slab; after compute, ds_write prefetched regs into the slab. HBM latency
// hides behind MFMA+ds_read compute.
// ---------------------------------------------------------------------------
__global__ __launch_bounds__(256, 2) void k3_tcn(const u16* __restrict__ H2,
                                                 const u16* __restrict__ Wb,
                                                 const float* __restrict__ tbg,
                                                 const float* __restrict__ fwg,
                                                 const float* __restrict__ fbg,
                                                 float* __restrict__ outg,
                                                 int b0, int Nc, int CBcur) {
  __shared__ __align__(16) char wlds[24576];
  __shared__ __align__(16) char hlds[4][8192];
  const int tid = threadIdx.x;
  const int n = blockIdx.x;
  const int w = tid >> 6, l = tid & 63;
  const int quad = l >> 4, lr = l & 15;
  const u16* Wp = Wb + (size_t)n * 12288;
#pragma unroll
  for (int c = 0; c < 6; ++c)
    gld_lds16(Wp + (c * 4 + w) * 512 + (size_t)l * 8, wlds + (c * 4 + w) * 1024);
  float tbv[4][4];
#pragma unroll
  for (int i = 0; i < 4; ++i)
#pragma unroll
    for (int r = 0; r < 4; ++r) tbv[i][r] = tbg[n * 64 + i * 16 + quad * 4 + r];
  const float fcb = fbg[0];
  f16x8 bz;
#pragma unroll
  for (int jj = 0; jj < 8; ++jj) bz[jj] = (_Float16)0.f;
  char* myl = hlds[w];
  // first slab for bp = w
  if (w < CBcur) {
    const u16* Hs0 = H2 + (size_t)n * Nc + w * 4096;
#pragma unroll
    for (int c = 0; c < 8; ++c)
      gld_lds16(Hs0 + c * 512 + (size_t)l * 8, myl + c * 1024);
  }
  asm volatile("s_waitcnt vmcnt(0)" ::: "memory");
  __syncthreads();
  const int lx7 = lr & 7;
  const f32x4 zz = {0.f, 0.f, 0.f, 0.f};
  for (int bp = w; bp < CBcur; bp += 4) {
    // prefetch next slab into registers (overlaps with compute below)
    const bool hasNext = (bp + 4) < CBcur;
    uint4 pf[8];
    if (hasNext) {
      const u16* Hn = H2 + (size_t)n * Nc + (bp + 4) * 4096;
#pragma unroll
      for (int c = 0; c < 8; ++c)
        pf[c] = *(const uint4*)(Hn + c * 512 + (size_t)l * 8);
    }
    f32x4 acc[4][4];
#pragma unroll
    for (int i = 0; i < 4; ++i)
#pragma unroll
      for (int j = 0; j < 4; ++j) acc[i][j] = zz;
#pragma unroll
    for (int ks = 0; ks < 2; ++ks)
#pragma unroll
      for (int kk = 0; kk < 3; ++kk) {
        const int usw = ((ks * 4 + quad) ^ lx7) << 4;
        f16x8 afr[4], bfr[4];
#pragma unroll
        for (int i = 0; i < 4; ++i)
          afr[i] = *(const f16x8*)(wlds + kk * 8192 + (i * 16 + lr) * 128 + usw);
#pragma unroll
        for (int j = 0; j < 4; ++j) {
          const int tau = j * 16 + lr + kk - 1;
          const int tc = min(max(tau, 0), 63);
          const int off = tc * 128 + (((ks * 4 + quad) ^ (tc & 7)) << 4);
          const f16x8 v = *(const f16x8*)(myl + off);
          bfr[j] = (tau == tc) ? v : bz;
        }
#pragma unroll
        for (int i = 0; i < 4; ++i)
#pragma unroll
          for (int j = 0; j < 4; ++j)
            acc[i][j] = __builtin_amdgcn_mfma_f32_16x16x32_f16(afr[i], bfr[j],
                                                               acc[i][j], 0, 0, 0);
      }
    float part = 0.f;
#pragma unroll
    for (int i = 0; i < 4; ++i)
#pragma unroll
      for (int r = 0; r < 4; ++r) {
        const int ho = i * 16 + quad * 4 + r;
        const float* fwp = fwg + ho * 64 + lr;
#pragma unroll
        for (int j = 0; j < 4; ++j)
          part += fmaxf(acc[i][j][r] + tbv[i][r], 0.f) * fwp[j * 16];
      }
#pragma unroll
    for (int off = 32; off > 0; off >>= 1) part += __shfl_xor(part, off, 64);
    if (l == 0) outg[(size_t)(b0 + bp) * NN + n] = part + fcb;
    if (hasNext) {
      // all ds_reads of my slab consumed (wave-local) before overwrite
      asm volatile("s_waitcnt lgkmcnt(0)" ::: "memory");
#pragma unroll
      for (int c = 0; c < 8; ++c)
        *(uint4*)(myl + c * 1024 + l * 16) = pf[c];
      asm volatile("s_waitcnt lgkmcnt(0)" ::: "memory");
    }
  }
}

// ---------------------------------------------------------------------------
extern "C" void kernel_launch(void* const* d_in, const int* in_sizes, int n_in,
                              void* d_out, int out_size, void* d_ws, size_t ws_size,
                              hipStream_t stream) {
  const float* xg   = (const float*)d_in[0];
  const float* adjg = (const float*)d_in[1];
  const float* w1g  = (const float*)d_in[2];
  const float* b1g  = (const float*)d_in[3];
  const float* w2g  = (const float*)d_in[4];
  const float* b2g  = (const float*)d_in[5];
  const float* twg  = (const float*)d_in[6];
  const float* tbg  = (const float*)d_in[7];
  const float* fwg  = (const float*)d_in[8];
  const float* fbg  = (const float*)d_in[9];
  float* outg = (float*)d_out;

  char* ws = (char*)d_ws;
  float* Sg = (float*)ws;                      // 4,194,304 B
  u16* adjb = (u16*)(ws + 4194304);            //   524,288 B
  u16* w2t  = (u16*)(ws + 4718592);            //     8,192 B (4KB used)
  u16* Wb   = (u16*)(ws + 4726784);            // 12,582,912 B
  const size_t fixedB = 17309696;
  int CB = 32;
  while (CB > 1 && fixedB + (size_t)CB * 4194304ull > ws_size) CB >>= 1;
  u16* H2g = (u16*)(ws + fixedB);              // CB*4096 cols x 512 rows
  const int Nc = CB * 4096;

  kcvt_adj<<<1024, 256, 0, stream>>>(adjg, adjb);
  kcvt_w2t<<<8, 256, 0, stream>>>(w2g, w2t);
  kcvt_w<<<24576, 256, 0, stream>>>(twg, Wb);
  k0_s<<<dim3(BB * TT / 64, NN / 64), 256, 0, stream>>>(xg, adjg, Sg);
  for (int b0 = 0; b0 < BB; b0 += CB) {
    k2_fused<<<dim3(4, Nc / 128), 256, 0, stream>>>(adjb, Sg, w1g, b1g, w2t, b2g,
                                                    H2g, Nc, b0);
    k3_tcn<<<dim3(NN), 256, 0, stream>>>(H2g, Wb, tbg, fwg, fbg, outg, b0, Nc, CB);
  }
}

// Round 13
// 279.142 us; speedup vs baseline: 1.6494x; 1.0057x over previous
//
#include <hip/hip_runtime.h>
#include <hip/hip_bf16.h>

#define BB 32
#define TT 64
#define NN 512
#define HH 64

using u16 = unsigned short;
using u32 = unsigned int;
typedef _Float16 f16x8 __attribute__((ext_vector_type(8)));
typedef _Float16 f16x2h __attribute__((ext_vector_type(2)));
typedef __fp16 fp16x2 __attribute__((ext_vector_type(2)));
typedef __attribute__((ext_vector_type(4))) float f32x4;

__device__ __forceinline__ u16 f2h_bits(float f) {
  _Float16 h = (_Float16)f;  // v_cvt_f16_f32, RNE, 1 instr
  u16 u; __builtin_memcpy(&u, &h, 2); return u;
}
__device__ __forceinline__ u32 pk2h(float a, float b) {  // v_cvt_pkrtz, 1 instr
  fp16x2 h = __builtin_amdgcn_cvt_pkrtz(a, b);
  u32 u; __builtin_memcpy(&u, &h, 4); return u;
}
__device__ __forceinline__ f16x2h pkh(float a, float b) {  // pkrtz -> _Float16 pair
  fp16x2 h = __builtin_amdgcn_cvt_pkrtz(a, b);
  f16x2h r; __builtin_memcpy(&r, &h, 4); return r;
}

// async global->LDS, 16B per lane; lds base wave-uniform, lane i lands at
// ldsbase + i*16; GLOBAL address is per-lane (must include lane term).
__device__ __forceinline__ void gld_lds16(const void* g, void* l) {
  __builtin_amdgcn_global_load_lds(
      (const __attribute__((address_space(1))) u32*)g,
      (__attribute__((address_space(3))) u32*)l, 16, 0, 0);
}

// ---------------------------------------------------------------------------
// conversion kernels (run once per call) — all outputs fp16
// ---------------------------------------------------------------------------
__global__ __launch_bounds__(256) void kcvt_adj(const float* __restrict__ a,
                                                u16* __restrict__ o) {
  const int i = blockIdx.x * 256 + threadIdx.x;  // 262144 total
  o[i] = f2h_bits(a[i]);
}
__global__ __launch_bounds__(256) void kcvt_w2t(const float* __restrict__ w2,
                                                u16* __restrict__ o) {
  const int i = blockIdx.x * 256 + threadIdx.x;  // 2048 total, o[h*32+c]
  const int h = i >> 5, c = i & 31;
  o[i] = f2h_bits(w2[c * 64 + h]);
}
// tcn_w [n][ho][hi][kk] (fp32) -> Wb [n][kk][ho][hi'] (f16), 16B unit of hi
// XOR-swizzled by (ho&7) so K3's linear LDS staging is conflict-free.
__global__ __launch_bounds__(256) void kcvt_w(const float* __restrict__ tw,
                                              u16* __restrict__ o) {
  const int i = blockIdx.x * 256 + threadIdx.x;  // 6291456 total
  const int his = i & 63;
  const int ho = (i >> 6) & 63;
  const int r = i >> 12;  // n*3 + kk
  const int n = r / 3, kk = r - n * 3;
  const int hi = (((his >> 3) ^ (ho & 7)) << 3) | (his & 7);
  o[i] = f2h_bits(tw[(n * 64 + ho) * 192 + hi * 3 + kk]);
}

// ---------------------------------------------------------------------------
// K0: S[bt][u] = sum_v X[bt][v] * adj[u][v]   (fp32 VALU, 1.07 GF — cheap)
// ---------------------------------------------------------------------------
__global__ __launch_bounds__(256) void k0_s(const float* __restrict__ xg,
                                            const float* __restrict__ adjg,
                                            float* __restrict__ Sg) {
  __shared__ __align__(16) float XsT[64][68];
  __shared__ __align__(16) float AdjT[64][68];
  const int tid = threadIdx.x;
  const int bt0 = blockIdx.x * 64, u0 = blockIdx.y * 64;
  const int ty = tid >> 4, tx = tid & 15;
  const int r = tid >> 2, cb = (tid & 3) << 4;
  float acc[4][4] = {};
  for (int v0 = 0; v0 < NN; v0 += 64) {
    {
      const float4* p = (const float4*)(xg + (((size_t)(bt0 + r)) << 9) + v0 + cb);
#pragma unroll
      for (int q = 0; q < 4; ++q) {
        float4 v = p[q];
        XsT[cb + q * 4 + 0][r] = v.x; XsT[cb + q * 4 + 1][r] = v.y;
        XsT[cb + q * 4 + 2][r] = v.z; XsT[cb + q * 4 + 3][r] = v.w;
      }
      const float4* pa = (const float4*)(adjg + (((size_t)(u0 + r)) << 9) + v0 + cb);
#pragma unroll
      for (int q = 0; q < 4; ++q) {
        float4 v = pa[q];
        AdjT[cb + q * 4 + 0][r] = v.x; AdjT[cb + q * 4 + 1][r] = v.y;
        AdjT[cb + q * 4 + 2][r] = v.z; AdjT[cb + q * 4 + 3][r] = v.w;
      }
    }
    __syncthreads();
#pragma unroll 8
    for (int v = 0; v < 64; ++v) {
      const float4 av = *(const float4*)&XsT[v][ty * 4];
      const float4 bv = *(const float4*)&AdjT[v][tx * 4];
      const float a[4] = {av.x, av.y, av.z, av.w};
      const float b[4] = {bv.x, bv.y, bv.z, bv.w};
#pragma unroll
      for (int i = 0; i < 4; ++i)
#pragma unroll
        for (int j = 0; j < 4; ++j) acc[i][j] += a[i] * b[j];
    }
    __syncthreads();
  }
#pragma unroll
  for (int i = 0; i < 4; ++i) {
    float4 o = {acc[i][0], acc[i][1], acc[i][2], acc[i][3]};
    *(float4*)&Sg[((size_t)(bt0 + ty * 4 + i)) * NN + u0 + tx * 4] = o;
  }
}

// ---------------------------------------------------------------------------
// K2 fused (K1+K2), fp16: C[u][n] = relu(sum_v adj[u][v]*G[n][v] + b2), with
// G panel built in-LDS per kt via small MFMAs; phi frags via native _Float16
// vector math (clang -> v_pk_fma_f16 / v_pk_max_f16, ~8 ops/frag).
// grid (tm=4, tn=Nc/128), 256 threads, 2x2 waves.
// ---------------------------------------------------------------------------
__global__ __launch_bounds__(256) void k2_fused(
    const u16* __restrict__ A, const float* __restrict__ Sg,
    const float* __restrict__ w1g, const float* __restrict__ b1g,
    const u16* __restrict__ w2t, const float* __restrict__ b2g,
    u16* __restrict__ C, int Nc, int b0) {
  __shared__ __align__(16) char smem[32768];  // As 16KB | Bs 16KB
  const int tid = threadIdx.x;
  const int w = tid >> 6, l = tid & 63;
  const int quad = l >> 4, lr = l & 15;
  const int tm = blockIdx.x, tn = blockIdx.y;
  const int m0 = tm * 128, n0 = tn * 128;
  const int wm = w >> 1, wn = w & 1;
  const int rB = w * 8 + (l >> 3);
  const int uu = l & 7;
  const u16* agp[4];
#pragma unroll
  for (int c = 0; c < 4; ++c) {
    const int r = rB + c * 32;
    agp[c] = A + (size_t)(m0 + r) * 512 + ((uu ^ (r & 7)) * 8);
  }
  char* As = smem;
  char* Bs = smem + 16384;
  const int t_loc = w & 1, vtb = (w >> 1) << 1;
  const int t = ((n0 >> 6) + t_loc) & 63;
  const int bp = n0 >> 12;
  const size_t sRow = ((size_t)((b0 + bp) * 64 + t)) << 9;
  // f16 vector w1/b1 for the quad's 8 channels
  f16x8 w1h, b1h, zero8;
#pragma unroll
  for (int j = 0; j < 8; ++j) {
    w1h[j] = (_Float16)w1g[quad * 8 + j];
    b1h[j] = (_Float16)b1g[quad * 8 + j];
    zero8[j] = (_Float16)0.f;
  }
  f16x8 wf[4];
#pragma unroll
  for (int ht = 0; ht < 4; ++ht)
    wf[ht] = *(const f16x8*)(w2t + (ht * 16 + lr) * 32 + quad * 8);
  int arow[4], brow[4];
#pragma unroll
  for (int i = 0; i < 4; ++i) {
    arow[i] = (wm * 64 + i * 16 + lr) * 128;
    brow[i] = (wn * 64 + i * 16 + lr) * 128;
  }
  const f32x4 zz = {0.f, 0.f, 0.f, 0.f};
  f32x4 acc[4][4];
#pragma unroll
  for (int i = 0; i < 4; ++i)
#pragma unroll
    for (int j = 0; j < 4; ++j) acc[i][j] = zz;
  const int lx7 = lr & 7;
  for (int kt = 0; kt < 8; ++kt) {
#pragma unroll
    for (int c = 0; c < 4; ++c)
      gld_lds16(agp[c] + kt * 64, As + (c * 32 + w * 8) * 128);
    // build B panel: G[row=t_loc*64+h][v-chunk] via MFMA, ds_write_b64
#pragma unroll
    for (int vi = 0; vi < 2; ++vi) {
      const int vt = vtb + vi;
      const float sv = Sg[sRow + kt * 64 + vt * 16 + lr];
      const _Float16 svh = (_Float16)sv;
      f16x8 svp;
#pragma unroll
      for (int j = 0; j < 8; ++j) svp[j] = svh;
      f16x8 afS = __builtin_elementwise_max(w1h * svp + b1h, zero8);
      const int qv = vt * 2 + (quad >> 1);
      const int bofs = ((qv ^ lx7) << 4) + ((quad & 1) << 3);
#pragma unroll
      for (int ht = 0; ht < 4; ++ht) {
        f32x4 p = __builtin_amdgcn_mfma_f32_16x16x32_f16(afS, wf[ht], zz, 0, 0, 0);
        uint2 st;
        st.x = pk2h(p[0], p[1]);
        st.y = pk2h(p[2], p[3]);
        const int row = t_loc * 64 + ht * 16 + lr;
        *(uint2*)(Bs + row * 128 + bofs) = st;
      }
    }
    __syncthreads();
#pragma unroll
    for (int ks = 0; ks < 2; ++ks) {
      const int coff = (((ks * 4 + quad) ^ lx7)) * 16;
      f16x8 afr[4], bfr[4];
#pragma unroll
      for (int i = 0; i < 4; ++i) afr[i] = *(const f16x8*)(As + arow[i] + coff);
#pragma unroll
      for (int j = 0; j < 4; ++j) bfr[j] = *(const f16x8*)(Bs + brow[j] + coff);
#pragma unroll
      for (int i = 0; i < 4; ++i)
#pragma unroll
        for (int j = 0; j < 4; ++j)
          acc[i][j] = __builtin_amdgcn_mfma_f32_16x16x32_f16(afr[i], bfr[j], acc[i][j], 0, 0, 0);
    }
    __syncthreads();
  }
  // epilogue: bias+relu, write with per-(t)-row XOR swizzle on 16B units
  const int nb = n0 + wn * 64;
  const int tcol = (nb >> 6) & 63;
  const int bpcol = nb >> 12;
  const int tx7 = tcol & 7;
  float bias[4];
#pragma unroll
  for (int j = 0; j < 4; ++j) bias[j] = b2g[j * 16 + lr];  // true h = j*16+lr
#pragma unroll
  for (int j = 0; j < 4; ++j) {
    const int h = j * 16 + lr;
    const int hsw = (((h >> 3) ^ tx7) << 3) | (h & 7);
    const size_t colb = (size_t)bpcol * 4096 + tcol * 64 + hsw;
#pragma unroll
    for (int i = 0; i < 4; ++i) {
      const int u0r = m0 + wm * 64 + i * 16 + quad * 4;
#pragma unroll
      for (int r = 0; r < 4; ++r) {
        const float vv = fmaxf(acc[i][j][r] + bias[j], 0.f);
        C[(size_t)(u0r + r) * Nc + colb] = f2h_bits(vv);
      }
    }
  }
}

// ---------------------------------------------------------------------------
// K3 (MFMA, fp16, software-pipelined): grid (NN) x 4 waves. W slab (24KB,
// pre-swizzled) in LDS once per block. Wave loops bp (= w + 4*it): PREFETCH
// next slab into VGPRs before computing current from its private 8KB LDS
// slab; after compute, ds_write prefetched regs into the slab.
// FC weights preloaded as packed f16 (no global loads in loop); FC dot via
// v_pk_fma_f16; reductions DEFERRED to one interleaved post-loop pass.
// ---------------------------------------------------------------------------
__global__ __launch_bounds__(256, 2) void k3_tcn(const u16* __restrict__ H2,
                                                 const u16* __restrict__ Wb,
                                                 const float* __restrict__ tbg,
                                                 const float* __restrict__ fwg,
                                                 const float* __restrict__ fbg,
                                                 float* __restrict__ outg,
                                                 int b0, int Nc, int CBcur) {
  __shared__ __align__(16) char wlds[24576];
  __shared__ __align__(16) char hlds[4][8192];
  const int tid = threadIdx.x;
  const int n = blockIdx.x;
  const int w = tid >> 6, l = tid & 63;
  const int quad = l >> 4, lr = l & 15;
  const u16* Wp = Wb + (size_t)n * 12288;
#pragma unroll
  for (int c = 0; c < 6; ++c)
    gld_lds16(Wp + (c * 4 + w) * 512 + (size_t)l * 8, wlds + (c * 4 + w) * 1024);
  float tbv[4][4];
#pragma unroll
  for (int i = 0; i < 4; ++i)
#pragma unroll
    for (int r = 0; r < 4; ++r) tbv[i][r] = tbg[n * 64 + i * 16 + quad * 4 + r];
  // FC weights: fwg[ho*64 + t] for the lane's 16 ho x 4 t, packed f16 pairs
  // fwh[i*4+r][0] = (t=lr, t=16+lr), [1] = (t=32+lr, t=48+lr)
  f16x2h fwh[16][2];
#pragma unroll
  for (int i = 0; i < 4; ++i)
#pragma unroll
    for (int r = 0; r < 4; ++r) {
      const float* fb = fwg + (i * 16 + quad * 4 + r) * 64 + lr;
      fwh[i * 4 + r][0] = pkh(fb[0], fb[16]);
      fwh[i * 4 + r][1] = pkh(fb[32], fb[48]);
    }
  const float fcb = fbg[0];
  f16x8 bz;
#pragma unroll
  for (int jj = 0; jj < 8; ++jj) bz[jj] = (_Float16)0.f;
  char* myl = hlds[w];
  // first slab for bp = w
  if (w < CBcur) {
    const u16* Hs0 = H2 + (size_t)n * Nc + w * 4096;
#pragma unroll
    for (int c = 0; c < 8; ++c)
      gld_lds16(Hs0 + c * 512 + (size_t)l * 8, myl + c * 1024);
  }
  asm volatile("s_waitcnt vmcnt(0)" ::: "memory");
  __syncthreads();
  const int lx7 = lr & 7;
  const f32x4 zz = {0.f, 0.f, 0.f, 0.f};
  float part[8] = {};
  for (int bp = w; bp < CBcur; bp += 4) {
    // prefetch next slab into registers (overlaps with compute below)
    const bool hasNext = (bp + 4) < CBcur;
    uint4 pf[8];
    if (hasNext) {
      const u16* Hn = H2 + (size_t)n * Nc + (bp + 4) * 4096;
#pragma unroll
      for (int c = 0; c < 8; ++c)
        pf[c] = *(const uint4*)(Hn + c * 512 + (size_t)l * 8);
    }
    f32x4 acc[4][4];
#pragma unroll
    for (int i = 0; i < 4; ++i)
#pragma unroll
      for (int j = 0; j < 4; ++j) acc[i][j] = zz;
#pragma unroll
    for (int ks = 0; ks < 2; ++ks)
#pragma unroll
      for (int kk = 0; kk < 3; ++kk) {
        const int usw = ((ks * 4 + quad) ^ lx7) << 4;
        f16x8 afr[4], bfr[4];
#pragma unroll
        for (int i = 0; i < 4; ++i)
          afr[i] = *(const f16x8*)(wlds + kk * 8192 + (i * 16 + lr) * 128 + usw);
#pragma unroll
        for (int j = 0; j < 4; ++j) {
          const int tau = j * 16 + lr + kk - 1;
          const int tc = min(max(tau, 0), 63);
          const int off = tc * 128 + (((ks * 4 + quad) ^ (tc & 7)) << 4);
          const f16x8 v = *(const f16x8*)(myl + off);
          bfr[j] = (tau == tc) ? v : bz;
        }
#pragma unroll
        for (int i = 0; i < 4; ++i)
#pragma unroll
          for (int j = 0; j < 4; ++j)
            acc[i][j] = __builtin_amdgcn_mfma_f32_16x16x32_f16(afr[i], bfr[j],
                                                               acc[i][j], 0, 0, 0);
      }
    // FC epilogue: bias+relu then packed-f16 dot with preloaded fw
    f16x2h pacc;
    pacc[0] = (_Float16)0.f; pacc[1] = (_Float16)0.f;
#pragma unroll
    for (int i = 0; i < 4; ++i)
#pragma unroll
      for (int r = 0; r < 4; ++r) {
        const float v0 = fmaxf(acc[i][0][r] + tbv[i][r], 0.f);
        const float v1 = fmaxf(acc[i][1][r] + tbv[i][r], 0.f);
        const float v2 = fmaxf(acc[i][2][r] + tbv[i][r], 0.f);
        const float v3 = fmaxf(acc[i][3][r] + tbv[i][r], 0.f);
        pacc = pkh(v0, v1) * fwh[i * 4 + r][0] + pacc;
        pacc = pkh(v2, v3) * fwh[i * 4 + r][1] + pacc;
      }
    part[(bp - w) >> 2] = (float)pacc[0] + (float)pacc[1];
    if (hasNext) {
      // all ds_reads of my slab consumed (wave-local) before overwrite
      asm volatile("s_waitcnt lgkmcnt(0)" ::: "memory");
#pragma unroll
      for (int c = 0; c < 8; ++c)
        *(uint4*)(myl + c * 1024 + l * 16) = pf[c];
      asm volatile("s_waitcnt lgkmcnt(0)" ::: "memory");
    }
  }
  // deferred reductions: 8 independent chains, interleaved per step
#pragma unroll
  for (int off = 32; off > 0; off >>= 1)
#pragma unroll
    for (int k = 0; k < 8; ++k) part[k] += __shfl_xor(part[k], off, 64);
  if (l == 0) {
#pragma unroll
    for (int k = 0; k < 8; ++k) {
      const int bp = w + k * 4;
      if (bp < CBcur) outg[(size_t)(b0 + bp) * NN + n] = part[k] + fcb;
    }
  }
}

// ---------------------------------------------------------------------------
extern "C" void kernel_launch(void* const* d_in, const int* in_sizes, int n_in,
                              void* d_out, int out_size, void* d_ws, size_t ws_size,
                              hipStream_t stream) {
  const float* xg   = (const float*)d_in[0];
  const float* adjg = (const float*)d_in[1];
  const float* w1g  = (const float*)d_in[2];
  const float* b1g  = (const float*)d_in[3];
  const float* w2g  = (const float*)d_in[4];
  const float* b2g  = (const float*)d_in[5];
  const float* twg  = (const float*)d_in[6];
  const float* tbg  = (const float*)d_in[7];
  const float* fwg  = (const float*)d_in[8];
  const float* fbg  = (const float*)d_in[9];
  float* outg = (float*)d_out;

  char* ws = (char*)d_ws;
  float* Sg = (float*)ws;                      // 4,194,304 B
  u16* adjb = (u16*)(ws + 4194304);            //   524,288 B
  u16* w2t  = (u16*)(ws + 4718592);            //     8,192 B (4KB used)
  u16* Wb   = (u16*)(ws + 4726784);            // 12,582,912 B
  const size_t fixedB = 17309696;
  int CB = 32;
  while (CB > 1 && fixedB + (size_t)CB * 4194304ull > ws_size) CB >>= 1;
  u16* H2g = (u16*)(ws + fixedB);              // CB*4096 cols x 512 rows
  const int Nc = CB * 4096;

  kcvt_adj<<<1024, 256, 0, stream>>>(adjg, adjb);
  kcvt_w2t<<<8, 256, 0, stream>>>(w2g, w2t);
  kcvt_w<<<24576, 256, 0, stream>>>(twg, Wb);
  k0_s<<<dim3(BB * TT / 64, NN / 64), 256, 0, stream>>>(xg, adjg, Sg);
  for (int b0 = 0; b0 < BB; b0 += CB) {
    k2_fused<<<dim3(4, Nc / 128), 256, 0, stream>>>(adjb, Sg, w1g, b1g, w2t, b2g,
                                                    H2g, Nc, b0);
    k3_tcn<<<dim3(NN), 256, 0, stream>>>(H2g, Wb, tbg, fwg, fbg, outg, b0, Nc, CB);
  }
}